// Round 1
// baseline (1296.054 us; speedup 1.0000x reference)
//
#include <hip/hip_runtime.h>
#include <math.h>

// Problem constants (B=2, S=2048, D=1024, H=16, Dk=64)
#define D_MODEL 1024
#define N_HEADS 16
#define D_K     64
#define BATCH   2
#define SEQ     2048
#define M_TOTAL (BATCH * SEQ)   // 4096

// ---------------------------------------------------------------------------
// GEMM: C = A(M,K) * B(N,K)^T  (both row-major; B is torch-style (out,in))
// BM=BN=64, BK=16, 256 threads, 4x4 micro-tile per thread.
// LAYOUT 0: C row-major [M][N]  (final output projection)
// LAYOUT 1: scatter to [b][h][s][dk] with m=b*2048+s, n=h*64+dk (q/k/v)
// LDS stride 68 floats: keeps float4 alignment, <=2-way bank conflicts.
// ---------------------------------------------------------------------------
template <int LAYOUT>
__global__ __launch_bounds__(256) void gemm_bt(const float* __restrict__ A,
                                               const float* __restrict__ B,
                                               float* __restrict__ C,
                                               int M, int N, int K)
{
    __shared__ float As[16][68];   // [k][m]
    __shared__ float Bs[16][68];   // [k][n]

    const int tid = threadIdx.x;
    const int tx = tid & 15;       // n / 4
    const int ty = tid >> 4;       // m / 4
    const int m0 = blockIdx.y * 64;
    const int n0 = blockIdx.x * 64;

    const int lrow = tid >> 2;        // 0..63 (tile row for staging)
    const int lk4  = (tid & 3) * 4;   // 0,4,8,12 (k offset for staging)

    float acc[4][4] = {{0.f}};

    for (int kb = 0; kb < K; kb += 16) {
        float4 av = *(const float4*)&A[(size_t)(m0 + lrow) * K + kb + lk4];
        float4 bv = *(const float4*)&B[(size_t)(n0 + lrow) * K + kb + lk4];
        __syncthreads();   // previous iteration's reads done before overwrite
        As[lk4 + 0][lrow] = av.x; As[lk4 + 1][lrow] = av.y;
        As[lk4 + 2][lrow] = av.z; As[lk4 + 3][lrow] = av.w;
        Bs[lk4 + 0][lrow] = bv.x; Bs[lk4 + 1][lrow] = bv.y;
        Bs[lk4 + 2][lrow] = bv.z; Bs[lk4 + 3][lrow] = bv.w;
        __syncthreads();

#pragma unroll
        for (int kk = 0; kk < 16; ++kk) {
            float4 a4 = *(const float4*)&As[kk][ty * 4];
            float4 b4 = *(const float4*)&Bs[kk][tx * 4];
            const float aa[4] = {a4.x, a4.y, a4.z, a4.w};
            const float bb[4] = {b4.x, b4.y, b4.z, b4.w};
#pragma unroll
            for (int i = 0; i < 4; ++i)
#pragma unroll
                for (int j = 0; j < 4; ++j)
                    acc[i][j] = fmaf(aa[i], bb[j], acc[i][j]);
        }
    }

    if (LAYOUT == 1) {
        // n0/64 == blockIdx.x == head index h; dk = tx*4 + j
        const int h = blockIdx.x;
#pragma unroll
        for (int i = 0; i < 4; ++i) {
            const int mrow = m0 + ty * 4 + i;
            const int b = mrow >> 11;          // /2048
            const int sq = mrow & 2047;
            float4 cv = {acc[i][0], acc[i][1], acc[i][2], acc[i][3]};
            *(float4*)&C[(((size_t)(b * N_HEADS + h) * SEQ) + sq) * D_K + tx * 4] = cv;
        }
    } else {
#pragma unroll
        for (int i = 0; i < 4; ++i) {
            float4 cv = {acc[i][0], acc[i][1], acc[i][2], acc[i][3]};
            *(float4*)&C[(size_t)(m0 + ty * 4 + i) * N + n0 + tx * 4] = cv;
        }
    }
}

// ---------------------------------------------------------------------------
// Flash attention (fp32), no mask. Q,K,V in [B,H,S,Dk]; out in [B,S,H*Dk].
// Block: 256 threads handle 32 q-rows; 8 lanes per row (g = lane group).
//   - lane owns keys kj = g + 8j (j=0..7)  -> staging rows stride spreads banks
//   - lane owns out dims d = g*8..g*8+7
// Row statistics reduced over the 8 contiguous lanes via __shfl_xor.
// LDS tiles stride 68 floats (float4-aligned, <=2-way conflicts on hot reads).
// ---------------------------------------------------------------------------
__global__ __launch_bounds__(256) void attn_fwd(const float* __restrict__ Q,
                                                const float* __restrict__ K,
                                                const float* __restrict__ V,
                                                float* __restrict__ O)
{
    __shared__ float Qs[32][68];
    __shared__ float Ks[64][68];
    __shared__ float Vs[64][68];
    __shared__ float Ps[32][68];

    const int tid = threadIdx.x;
    const int r = tid >> 3;    // q-row within tile, 0..31
    const int g = tid & 7;     // lane group, 0..7
    const int b = blockIdx.z;
    const int h = blockIdx.y;
    const int bh = b * N_HEADS + h;
    const int q0 = blockIdx.x * 32;

    const float* Qp = Q + ((size_t)bh * SEQ + q0) * D_K;
    const float* Kp = K + (size_t)bh * SEQ * D_K;
    const float* Vp = V + (size_t)bh * SEQ * D_K;

    // Stage Q tile (32x64), pre-scaled by 1/sqrt(Dk) = 0.125
    {
        int idx = tid;
#pragma unroll
        for (int it = 0; it < 2; ++it, idx += 256) {
            int row = idx >> 4;       // 16 float4 per row
            int c4 = idx & 15;
            float4 v = *(const float4*)&Qp[row * D_K + c4 * 4];
            v.x *= 0.125f; v.y *= 0.125f; v.z *= 0.125f; v.w *= 0.125f;
            *(float4*)&Qs[row][c4 * 4] = v;
        }
    }

    float m = -INFINITY;
    float l = 0.f;
    float o[8] = {0.f, 0.f, 0.f, 0.f, 0.f, 0.f, 0.f, 0.f};

    for (int kt = 0; kt < SEQ / 64; ++kt) {
        __syncthreads();   // prior PV reads (and Q staging) done
        // Stage K,V tiles (64x64 each)
#pragma unroll
        for (int it = 0; it < 4; ++it) {
            int idx = tid + it * 256;
            int row = idx >> 4;
            int c4 = idx & 15;
            *(float4*)&Ks[row][c4 * 4] =
                *(const float4*)&Kp[(size_t)(kt * 64 + row) * D_K + c4 * 4];
            *(float4*)&Vs[row][c4 * 4] =
                *(const float4*)&Vp[(size_t)(kt * 64 + row) * D_K + c4 * 4];
        }
        __syncthreads();

        // Scores: s[j] = (q_r . k_{g+8j}) (Q pre-scaled)
        float s[8] = {0.f, 0.f, 0.f, 0.f, 0.f, 0.f, 0.f, 0.f};
#pragma unroll
        for (int d4 = 0; d4 < 16; ++d4) {
            float4 q4 = *(const float4*)&Qs[r][d4 * 4];
#pragma unroll
            for (int j = 0; j < 8; ++j) {
                float4 k4 = *(const float4*)&Ks[g + 8 * j][d4 * 4];
                s[j] = fmaf(q4.x, k4.x, s[j]);
                s[j] = fmaf(q4.y, k4.y, s[j]);
                s[j] = fmaf(q4.z, k4.z, s[j]);
                s[j] = fmaf(q4.w, k4.w, s[j]);
            }
        }

        // Online softmax: row max over this tile
        float mloc = s[0];
#pragma unroll
        for (int j = 1; j < 8; ++j) mloc = fmaxf(mloc, s[j]);
#pragma unroll
        for (int off = 1; off < 8; off <<= 1)
            mloc = fmaxf(mloc, __shfl_xor(mloc, off, 64));

        const float mnew = fmaxf(m, mloc);
        const float sc = __expf(m - mnew);   // 0 on first tile (m = -inf)

        float lloc = 0.f;
#pragma unroll
        for (int j = 0; j < 8; ++j) {
            float p = __expf(s[j] - mnew);
            Ps[r][g + 8 * j] = p;
            lloc += p;
        }
#pragma unroll
        for (int off = 1; off < 8; off <<= 1)
            lloc += __shfl_xor(lloc, off, 64);

        l = l * sc + lloc;
        m = mnew;
#pragma unroll
        for (int i = 0; i < 8; ++i) o[i] *= sc;

        __syncthreads();   // Ps visible to the row's lanes

        // PV: o[d] += sum_kj P[r][kj] * V[kj][d],  d = g*8 + i
#pragma unroll
        for (int k4 = 0; k4 < 16; ++k4) {
            float4 p4 = *(const float4*)&Ps[r][k4 * 4];
            const float pv[4] = {p4.x, p4.y, p4.z, p4.w};
#pragma unroll
            for (int c = 0; c < 4; ++c) {
                const float* vrow = &Vs[k4 * 4 + c][g * 8];
                float4 va = *(const float4*)&vrow[0];
                float4 vb = *(const float4*)&vrow[4];
                const float p = pv[c];
                o[0] = fmaf(p, va.x, o[0]);
                o[1] = fmaf(p, va.y, o[1]);
                o[2] = fmaf(p, va.z, o[2]);
                o[3] = fmaf(p, va.w, o[3]);
                o[4] = fmaf(p, vb.x, o[4]);
                o[5] = fmaf(p, vb.y, o[5]);
                o[6] = fmaf(p, vb.z, o[6]);
                o[7] = fmaf(p, vb.w, o[7]);
            }
        }
    }

    // Normalize and write out in [b][s][h*64+dk] layout
    const float inv = 1.f / l;
    float4 o0 = {o[0] * inv, o[1] * inv, o[2] * inv, o[3] * inv};
    float4 o1 = {o[4] * inv, o[5] * inv, o[6] * inv, o[7] * inv};
    float* Op = O + ((size_t)(b * SEQ + q0 + r)) * D_MODEL + h * D_K + g * 8;
    *(float4*)&Op[0] = o0;
    *(float4*)&Op[4] = o1;
}

// ---------------------------------------------------------------------------
// Launch: QKV projections -> flash attention -> output projection.
// Workspace: q,k,v in [B,H,S,Dk] fp32 (16 MB each) + attn-out [B,S,D] (16 MB)
//            = 64 MB of d_ws.
// ---------------------------------------------------------------------------
extern "C" void kernel_launch(void* const* d_in, const int* in_sizes, int n_in,
                              void* d_out, int out_size, void* d_ws, size_t ws_size,
                              hipStream_t stream)
{
    const float* x  = (const float*)d_in[0];
    const float* Wq = (const float*)d_in[1];
    const float* Wk = (const float*)d_in[2];
    const float* Wv = (const float*)d_in[3];
    const float* Wo = (const float*)d_in[4];
    float* out = (float*)d_out;

    float* q  = (float*)d_ws;                       // [B,H,S,Dk]
    float* k  = q + (size_t)M_TOTAL * D_MODEL;      // +4,194,304
    float* v  = k + (size_t)M_TOTAL * D_MODEL;
    float* ao = v + (size_t)M_TOTAL * D_MODEL;      // [B,S,D]

    const dim3 gblk(256);
    const dim3 ggrid(D_MODEL / 64, M_TOTAL / 64);   // (16, 64)

    hipLaunchKernelGGL((gemm_bt<1>), ggrid, gblk, 0, stream,
                       x, Wq, q, M_TOTAL, D_MODEL, D_MODEL);
    hipLaunchKernelGGL((gemm_bt<1>), ggrid, gblk, 0, stream,
                       x, Wk, k, M_TOTAL, D_MODEL, D_MODEL);
    hipLaunchKernelGGL((gemm_bt<1>), ggrid, gblk, 0, stream,
                       x, Wv, v, M_TOTAL, D_MODEL, D_MODEL);

    const dim3 agrid(SEQ / 32, N_HEADS, BATCH);     // (64, 16, 2)
    hipLaunchKernelGGL(attn_fwd, agrid, gblk, 0, stream, q, k, v, ao);

    hipLaunchKernelGGL((gemm_bt<0>), ggrid, gblk, 0, stream,
                       ao, Wo, out, M_TOTAL, D_MODEL, D_MODEL);
}

// Round 2
// 247.257 us; speedup vs baseline: 5.2417x; 5.2417x over previous
//
#include <hip/hip_runtime.h>
#include <hip/hip_bf16.h>
#include <math.h>

#define D_MODEL 1024
#define N_HEADS 16
#define D_K     64
#define BATCH   2
#define SEQ     2048
#define M_TOTAL (BATCH * SEQ)   // 4096

typedef __attribute__((ext_vector_type(8))) short short8;   // 8 bf16 = 4 VGPR
typedef __attribute__((ext_vector_type(4))) float f32x4;

__device__ __forceinline__ ushort f2bf(float f) {
    __hip_bfloat16 h = __float2bfloat16(f);
    union { __hip_bfloat16 h; ushort u; } c; c.h = h; return c.u;
}

__device__ __forceinline__ void gload_lds16(const void* g, void* l) {
    __builtin_amdgcn_global_load_lds(
        (const __attribute__((address_space(1))) void*)g,
        (__attribute__((address_space(3))) void*)l, 16, 0, 0);
}

// ---------------------------------------------------------------------------
// f32 -> bf16 cast (n multiple of 4)
// ---------------------------------------------------------------------------
__global__ __launch_bounds__(256) void cast_bf16(const float* __restrict__ in,
                                                 ushort* __restrict__ out, int n)
{
    int i = (blockIdx.x * 256 + threadIdx.x) * 4;
    if (i >= n) return;
    float4 v = *(const float4*)&in[i];
    ushort4 o;
    o.x = f2bf(v.x); o.y = f2bf(v.y); o.z = f2bf(v.z); o.w = f2bf(v.w);
    *(ushort4*)&out[i] = o;
}

// ---------------------------------------------------------------------------
// bf16 GEMM: C = A(M,K) * B(N,K)^T, fp32 accum via mfma_f32_16x16x32_bf16.
// 128x128 tile, BK=32, 256 thr (4 waves, 2x2 of 64x64), global_load_lds w=16.
// LDS layout [kgroup(4)][row(128)][8 bf16] -> conflict-free ds_read_b128.
// EPI 0: C fp32 row-major [M][N].
// EPI 1: QKV scatter to bf16 [B,H,S,Dk]; proj 0 (q) scaled by 0.125.
// ---------------------------------------------------------------------------
template <int EPI>
__global__ __launch_bounds__(256) void gemm_bf16(const ushort* __restrict__ A,
                                                 const ushort* __restrict__ B,
                                                 void* __restrict__ C0,
                                                 void* __restrict__ C1,
                                                 void* __restrict__ C2,
                                                 int M, int N, int K)
{
    __shared__ ushort As[4 * 128 * 8];
    __shared__ ushort Bs[4 * 128 * 8];

    const int tid = threadIdx.x;
    const int lane = tid & 63;
    const int w = tid >> 6;
    const int li = lane & 15;
    const int kg = lane >> 4;
    const int m0 = blockIdx.y * 128;
    const int n0 = blockIdx.x * 128;
    const int wr = (w >> 1) * 64;
    const int wc = (w & 1) * 64;

    f32x4 acc[4][4] = {};

    // staging slots: slot s (16 B) = [kgroup = s>>7][row = s&127]
    const int s1 = tid, s2 = tid + 256;
    const ushort* ga1 = &A[(size_t)(m0 + (s1 & 127)) * K + (s1 >> 7) * 8];
    const ushort* ga2 = &A[(size_t)(m0 + (s2 & 127)) * K + (s2 >> 7) * 8];
    const ushort* gb1 = &B[(size_t)(n0 + (s1 & 127)) * K + (s1 >> 7) * 8];
    const ushort* gb2 = &B[(size_t)(n0 + (s2 & 127)) * K + (s2 >> 7) * 8];
    ushort* lA1 = &As[s1 * 8]; ushort* lA2 = &As[s2 * 8];
    ushort* lB1 = &Bs[s1 * 8]; ushort* lB2 = &Bs[s2 * 8];

    for (int kb = 0; kb < K; kb += 32) {
        __syncthreads();                 // prior frag reads done before overwrite
        gload_lds16(ga1 + kb, lA1);
        gload_lds16(ga2 + kb, lA2);
        gload_lds16(gb1 + kb, lB1);
        gload_lds16(gb2 + kb, lB2);
        __syncthreads();                 // vmcnt drained before barrier

        short8 af[4], bf_[4];
#pragma unroll
        for (int m = 0; m < 4; ++m)
            af[m] = *(const short8*)&As[(kg * 128 + wr + m * 16 + li) * 8];
#pragma unroll
        for (int n = 0; n < 4; ++n)
            bf_[n] = *(const short8*)&Bs[(kg * 128 + wc + n * 16 + li) * 8];
#pragma unroll
        for (int m = 0; m < 4; ++m)
#pragma unroll
            for (int n = 0; n < 4; ++n)
                acc[m][n] = __builtin_amdgcn_mfma_f32_16x16x32_bf16(
                    af[m], bf_[n], acc[m][n], 0, 0, 0);
    }

    // Epilogue. D layout: col = lane&15, row = (lane>>4)*4 + reg  [m89-verified]
    if (EPI == 1) {
        ushort* q = (ushort*)C0; ushort* k = (ushort*)C1; ushort* v = (ushort*)C2;
#pragma unroll
        for (int m = 0; m < 4; ++m) {
            const int Rb = m0 + wr + m * 16 + kg * 4;
#pragma unroll
            for (int n = 0; n < 4; ++n) {
                const int Ncol = n0 + wc + n * 16 + li;
                const int proj = Ncol >> 10;
                const int rem = Ncol & 1023;
                const int h = rem >> 6, dk = rem & 63;
                ushort* dst = proj == 0 ? q : (proj == 1 ? k : v);
                const float scale = (proj == 0) ? 0.125f : 1.0f;
#pragma unroll
                for (int r = 0; r < 4; ++r) {
                    const int R = Rb + r;
                    const int b = R >> 11, s = R & 2047;
                    dst[(((size_t)(b * N_HEADS + h) * SEQ) + s) * D_K + dk] =
                        f2bf(acc[m][n][r] * scale);
                }
            }
        }
    } else {
        float* C = (float*)C0;
#pragma unroll
        for (int m = 0; m < 4; ++m) {
            const int Rb = m0 + wr + m * 16 + kg * 4;
#pragma unroll
            for (int n = 0; n < 4; ++n) {
                const int Ncol = n0 + wc + n * 16 + li;
#pragma unroll
                for (int r = 0; r < 4; ++r)
                    C[(size_t)(Rb + r) * N + Ncol] = acc[m][n][r];
            }
        }
    }
}

// ---------------------------------------------------------------------------
// MFMA flash attention. Q,K,V bf16 [B,H,S,Dk] (Q pre-scaled by 0.125).
// Block: 256 thr = 4 waves; wave w owns q rows [q0+w*16, q0+w*16+16).
// KV tile = 64 keys. K staged [64][72] bf16 (144 B stride, conflict-free);
// V staged transposed Vt[64 d][72]; P via padded LDS per-wave for PV frags.
// fp32 online softmax, 16-lane shfl_xor reduce. Out: bf16 ao[B,S,D].
// ---------------------------------------------------------------------------
__global__ __launch_bounds__(256) void attn_mfma(const ushort* __restrict__ Q,
                                                 const ushort* __restrict__ K,
                                                 const ushort* __restrict__ V,
                                                 ushort* __restrict__ AO)
{
    __shared__ ushort Ks[64 * 72];
    __shared__ ushort Vt[64 * 72];
    __shared__ ushort Ps[4 * 16 * 72];

    const int tid = threadIdx.x, lane = tid & 63, w = tid >> 6;
    const int li = lane & 15, g = lane >> 4;
    const int b = blockIdx.z, h = blockIdx.y, q0 = blockIdx.x * 64;
    const int bh = b * N_HEADS + h;
    const size_t base = (size_t)bh * SEQ * D_K;

    // Q fragments in registers (A-frag: row = lane&15, k = (lane>>4)*8+j)
    const size_t qrow = base + (size_t)(q0 + w * 16 + li) * D_K;
    const short8 qa0 = *(const short8*)&Q[qrow + g * 8];
    const short8 qa1 = *(const short8*)&Q[qrow + 32 + g * 8];

    float m_[4] = {-INFINITY, -INFINITY, -INFINITY, -INFINITY};
    float l_[4] = {0.f, 0.f, 0.f, 0.f};
    f32x4 o[4] = {};

    // staging assignment: thread -> K/V row (t>>2), col block (t&3)*16
    const int srow = tid >> 2, sc0 = (tid & 3) * 16;
    const ushort* Kg = &K[base + (size_t)srow * D_K + sc0];
    const ushort* Vg = &V[base + (size_t)srow * D_K + sc0];
    ushort* KsW = &Ks[srow * 72 + sc0];
    ushort* Pw = &Ps[w * 16 * 72];

    for (int kt = 0; kt < SEQ / 64; ++kt) {
        __syncthreads();                           // prior tile reads done
        const size_t toff = (size_t)kt * 64 * D_K;
        short8 k0 = *(const short8*)(Kg + toff);
        short8 k1 = *(const short8*)(Kg + toff + 8);
        short8 v0 = *(const short8*)(Vg + toff);
        short8 v1 = *(const short8*)(Vg + toff + 8);
        *(short8*)(KsW) = k0;
        *(short8*)(KsW + 8) = k1;
#pragma unroll
        for (int i = 0; i < 8; ++i) {
            Vt[(sc0 + i) * 72 + srow] = (ushort)v0[i];
            Vt[(sc0 + 8 + i) * 72 + srow] = (ushort)v1[i];
        }
        __syncthreads();

        // QK^T: S[16 q][64 keys] in 4 frags; B-frag from Ks (col=key, k=dk)
        f32x4 s4[4];
#pragma unroll
        for (int kf = 0; kf < 4; ++kf) {
            short8 kb0 = *(const short8*)&Ks[(kf * 16 + li) * 72 + g * 8];
            short8 kb1 = *(const short8*)&Ks[(kf * 16 + li) * 72 + 32 + g * 8];
            f32x4 z = {0.f, 0.f, 0.f, 0.f};
            z = __builtin_amdgcn_mfma_f32_16x16x32_bf16(qa0, kb0, z, 0, 0, 0);
            z = __builtin_amdgcn_mfma_f32_16x16x32_bf16(qa1, kb1, z, 0, 0, 0);
            s4[kf] = z;
        }

        // online softmax; lane holds rows g*4+r, cols kf*16+li
        float p[4][4];
#pragma unroll
        for (int r = 0; r < 4; ++r) {
            float mx = fmaxf(fmaxf(s4[0][r], s4[1][r]), fmaxf(s4[2][r], s4[3][r]));
#pragma unroll
            for (int off = 1; off < 16; off <<= 1)
                mx = fmaxf(mx, __shfl_xor(mx, off, 64));
            const float mn = fmaxf(m_[r], mx);
            const float scale = __expf(m_[r] - mn);
            float ts = 0.f;
#pragma unroll
            for (int kf = 0; kf < 4; ++kf) {
                const float pe = __expf(s4[kf][r] - mn);
                p[kf][r] = pe; ts += pe;
            }
#pragma unroll
            for (int off = 1; off < 16; off <<= 1)
                ts += __shfl_xor(ts, off, 64);
            l_[r] = l_[r] * scale + ts;
            m_[r] = mn;
#pragma unroll
            for (int df = 0; df < 4; ++df) o[df][r] *= scale;
        }

        // P -> per-wave LDS (bf16), re-fragment for PV
#pragma unroll
        for (int r = 0; r < 4; ++r)
#pragma unroll
            for (int kf = 0; kf < 4; ++kf)
                Pw[(g * 4 + r) * 72 + kf * 16 + li] = f2bf(p[kf][r]);
        asm volatile("s_waitcnt lgkmcnt(0)" ::: "memory");
        __builtin_amdgcn_sched_barrier(0);

        // PV: A-frag from Pw (row=li, k=key), B-frag from Vt (col=d, k=key)
        const short8 pa0 = *(const short8*)&Pw[li * 72 + g * 8];
        const short8 pa1 = *(const short8*)&Pw[li * 72 + 32 + g * 8];
#pragma unroll
        for (int df = 0; df < 4; ++df) {
            short8 vb0 = *(const short8*)&Vt[(df * 16 + li) * 72 + g * 8];
            short8 vb1 = *(const short8*)&Vt[(df * 16 + li) * 72 + 32 + g * 8];
            o[df] = __builtin_amdgcn_mfma_f32_16x16x32_bf16(pa0, vb0, o[df], 0, 0, 0);
            o[df] = __builtin_amdgcn_mfma_f32_16x16x32_bf16(pa1, vb1, o[df], 0, 0, 0);
        }
    }

    // normalize, store ao[b][q0+w*16+g*4+r][h*64 + df*16 + li]
    float inv[4];
#pragma unroll
    for (int r = 0; r < 4; ++r) inv[r] = 1.0f / l_[r];
#pragma unroll
    for (int df = 0; df < 4; ++df)
#pragma unroll
        for (int r = 0; r < 4; ++r) {
            const size_t row = (size_t)b * SEQ + q0 + w * 16 + g * 4 + r;
            AO[row * D_MODEL + h * 64 + df * 16 + li] = f2bf(o[df][r] * inv[r]);
        }
}

// ---------------------------------------------------------------------------
extern "C" void kernel_launch(void* const* d_in, const int* in_sizes, int n_in,
                              void* d_out, int out_size, void* d_ws, size_t ws_size,
                              hipStream_t stream)
{
    const float* x  = (const float*)d_in[0];
    const float* Wq = (const float*)d_in[1];
    const float* Wk = (const float*)d_in[2];
    const float* Wv = (const float*)d_in[3];
    const float* Wo = (const float*)d_in[4];
    float* out = (float*)d_out;

    // bf16 workspace layout
    ushort* xb   = (ushort*)d_ws;                       // [4096][1024]
    ushort* Wqkv = xb + (size_t)M_TOTAL * D_MODEL;      // [3072][1024]
    ushort* Wob  = Wqkv + (size_t)3 * D_MODEL * D_MODEL;// [1024][1024]
    ushort* q    = Wob + (size_t)D_MODEL * D_MODEL;     // [B,H,S,Dk]
    ushort* k    = q + (size_t)M_TOTAL * D_MODEL;
    ushort* v    = k + (size_t)M_TOTAL * D_MODEL;
    ushort* ao   = v + (size_t)M_TOTAL * D_MODEL;       // [B,S,D]

    const int NW = D_MODEL * D_MODEL;                   // 1M elements
    hipLaunchKernelGGL(cast_bf16, dim3(M_TOTAL * D_MODEL / 1024), dim3(256), 0, stream,
                       x, xb, M_TOTAL * D_MODEL);
    hipLaunchKernelGGL(cast_bf16, dim3(NW / 1024), dim3(256), 0, stream, Wq, Wqkv, NW);
    hipLaunchKernelGGL(cast_bf16, dim3(NW / 1024), dim3(256), 0, stream, Wk, Wqkv + NW, NW);
    hipLaunchKernelGGL(cast_bf16, dim3(NW / 1024), dim3(256), 0, stream, Wv, Wqkv + 2 * NW, NW);
    hipLaunchKernelGGL(cast_bf16, dim3(NW / 1024), dim3(256), 0, stream, Wo, Wob, NW);

    // fused QKV projection: [4096,1024] @ [3072,1024]^T -> scatter q,k,v
    hipLaunchKernelGGL((gemm_bf16<1>), dim3(3 * D_MODEL / 128, M_TOTAL / 128), dim3(256),
                       0, stream, xb, Wqkv, q, k, v, M_TOTAL, 3 * D_MODEL, D_MODEL);

    // flash attention
    hipLaunchKernelGGL(attn_mfma, dim3(SEQ / 64, N_HEADS, BATCH), dim3(256),
                       0, stream, q, k, v, ao);

    // output projection: [4096,1024] @ [1024,1024]^T -> fp32 out
    hipLaunchKernelGGL((gemm_bf16<0>), dim3(D_MODEL / 128, M_TOTAL / 128), dim3(256),
                       0, stream, ao, Wob, out, (void*)0, (void*)0,
                       M_TOTAL, D_MODEL, D_MODEL);
}

// Round 3
// 234.501 us; speedup vs baseline: 5.5269x; 1.0544x over previous
//
#include <hip/hip_runtime.h>
#include <hip/hip_bf16.h>
#include <math.h>

#define D_MODEL 1024
#define N_HEADS 16
#define D_K     64
#define BATCH   2
#define SEQ     2048
#define M_TOTAL (BATCH * SEQ)   // 4096

typedef __attribute__((ext_vector_type(8))) short short8;   // 8 bf16 = 4 VGPR
typedef __attribute__((ext_vector_type(4))) float f32x4;

__device__ __forceinline__ ushort f2bf(float f) {
    __hip_bfloat16 h = __float2bfloat16(f);
    union { __hip_bfloat16 h; ushort u; } c; c.h = h; return c.u;
}

__device__ __forceinline__ void gload_lds16(const void* g, void* l) {
    __builtin_amdgcn_global_load_lds(
        (const __attribute__((address_space(1))) void*)g,
        (__attribute__((address_space(3))) void*)l, 16, 0, 0);
}

// ---------------------------------------------------------------------------
// Fused f32 -> bf16 cast for all 5 tensors in one launch.
// Blocks 0..4095: x (4M); then 1024 each for Wq, Wk, Wv, Wo.
// ---------------------------------------------------------------------------
__global__ __launch_bounds__(256) void cast_all(const float* __restrict__ x,
                                                const float* __restrict__ Wq,
                                                const float* __restrict__ Wk,
                                                const float* __restrict__ Wv,
                                                const float* __restrict__ Wo,
                                                ushort* __restrict__ xb,
                                                ushort* __restrict__ wqkv,
                                                ushort* __restrict__ wob)
{
    const int bi = blockIdx.x;
    const float* src; ushort* dst; int blk;
    const int NW = D_MODEL * D_MODEL;  // 1M
    if (bi < 4096)      { src = x;  dst = xb;            blk = bi; }
    else if (bi < 5120) { src = Wq; dst = wqkv;          blk = bi - 4096; }
    else if (bi < 6144) { src = Wk; dst = wqkv + NW;     blk = bi - 5120; }
    else if (bi < 7168) { src = Wv; dst = wqkv + 2 * NW; blk = bi - 6144; }
    else                { src = Wo; dst = wob;           blk = bi - 7168; }
    const int i = blk * 1024 + threadIdx.x * 4;
    float4 v = *(const float4*)&src[i];
    ushort4 o;
    o.x = f2bf(v.x); o.y = f2bf(v.y); o.z = f2bf(v.z); o.w = f2bf(v.w);
    *(ushort4*)&dst[i] = o;
}

// ---------------------------------------------------------------------------
// bf16 GEMM: C = A(M,K) * B(N,K)^T, fp32 accum via mfma_f32_16x16x32_bf16.
// 128x128 tile, BK=32, 256 thr (4 waves), global_load_lds w=16,
// double-buffered LDS with vmcnt-before-barrier prefetch (T3-minimum).
// EPI 0: C fp32 row-major [M][N].
// EPI 1: QKV scatter: q,k bf16 [B,H,S,Dk] (q scaled 0.125); v bf16 [B,H,Dk,S].
// ---------------------------------------------------------------------------
template <int EPI>
__global__ __launch_bounds__(256) void gemm_bf16(const ushort* __restrict__ A,
                                                 const ushort* __restrict__ B,
                                                 void* __restrict__ C0,
                                                 void* __restrict__ C1,
                                                 void* __restrict__ C2,
                                                 int M, int N, int K)
{
    __shared__ ushort As[2][4 * 128 * 8];
    __shared__ ushort Bs[2][4 * 128 * 8];

    const int tid = threadIdx.x;
    const int lane = tid & 63;
    const int w = tid >> 6;
    const int li = lane & 15;
    const int kg = lane >> 4;
    const int m0 = blockIdx.y * 128;
    const int n0 = blockIdx.x * 128;
    const int wr = (w >> 1) * 64;
    const int wc = (w & 1) * 64;

    f32x4 acc[4][4] = {};

    // staging chunk s (16 B) = [kgroup = s>>7][row = s&127]
    const int s1 = tid, s2 = tid + 256;
    const ushort* ga1 = &A[(size_t)(m0 + (s1 & 127)) * K + (s1 >> 7) * 8];
    const ushort* ga2 = &A[(size_t)(m0 + (s2 & 127)) * K + (s2 >> 7) * 8];
    const ushort* gb1 = &B[(size_t)(n0 + (s1 & 127)) * K + (s1 >> 7) * 8];
    const ushort* gb2 = &B[(size_t)(n0 + (s2 & 127)) * K + (s2 >> 7) * 8];

    const int NT = K / 32;
    // prologue: stage tile 0 into buf 0
    gload_lds16(ga1, &As[0][s1 * 8]);
    gload_lds16(ga2, &As[0][s2 * 8]);
    gload_lds16(gb1, &Bs[0][s1 * 8]);
    gload_lds16(gb2, &Bs[0][s2 * 8]);

    for (int t = 0; t < NT; ++t) {
        const int cur = t & 1;
        asm volatile("s_waitcnt vmcnt(0)" ::: "memory");
        __syncthreads();
        if (t + 1 < NT) {
            const int kb = (t + 1) * 32;
            const int nxt = cur ^ 1;
            gload_lds16(ga1 + kb, &As[nxt][s1 * 8]);
            gload_lds16(ga2 + kb, &As[nxt][s2 * 8]);
            gload_lds16(gb1 + kb, &Bs[nxt][s1 * 8]);
            gload_lds16(gb2 + kb, &Bs[nxt][s2 * 8]);
        }
        short8 af[4], bf_[4];
#pragma unroll
        for (int m = 0; m < 4; ++m)
            af[m] = *(const short8*)&As[cur][(kg * 128 + wr + m * 16 + li) * 8];
#pragma unroll
        for (int n = 0; n < 4; ++n)
            bf_[n] = *(const short8*)&Bs[cur][(kg * 128 + wc + n * 16 + li) * 8];
#pragma unroll
        for (int m = 0; m < 4; ++m)
#pragma unroll
            for (int n = 0; n < 4; ++n)
                acc[m][n] = __builtin_amdgcn_mfma_f32_16x16x32_bf16(
                    af[m], bf_[n], acc[m][n], 0, 0, 0);
    }

    // Epilogue. D layout: col = lane&15, row = (lane>>4)*4 + reg  [m89-verified]
    if (EPI == 1) {
        ushort* q = (ushort*)C0; ushort* k = (ushort*)C1; ushort* v = (ushort*)C2;
#pragma unroll
        for (int m = 0; m < 4; ++m) {
            const int Rb = m0 + wr + m * 16 + kg * 4;
#pragma unroll
            for (int n = 0; n < 4; ++n) {
                const int Ncol = n0 + wc + n * 16 + li;
                const int proj = Ncol >> 10;
                const int rem = Ncol & 1023;
                const int h = rem >> 6, dk = rem & 63;
#pragma unroll
                for (int r = 0; r < 4; ++r) {
                    const int R = Rb + r;
                    const int b = R >> 11, s = R & 2047;
                    const int bh = b * N_HEADS + h;
                    if (proj == 0)
                        q[((size_t)bh * SEQ + s) * D_K + dk] = f2bf(acc[m][n][r] * 0.125f);
                    else if (proj == 1)
                        k[((size_t)bh * SEQ + s) * D_K + dk] = f2bf(acc[m][n][r]);
                    else  // V stored transposed: [B,H,Dk,S]
                        v[((size_t)bh * D_K + dk) * SEQ + s] = f2bf(acc[m][n][r]);
                }
            }
        }
    } else {
        float* C = (float*)C0;
#pragma unroll
        for (int m = 0; m < 4; ++m) {
            const int Rb = m0 + wr + m * 16 + kg * 4;
#pragma unroll
            for (int n = 0; n < 4; ++n) {
                const int Ncol = n0 + wc + n * 16 + li;
#pragma unroll
                for (int r = 0; r < 4; ++r)
                    C[(size_t)(Rb + r) * N + Ncol] = acc[m][n][r];
            }
        }
    }
}

// ---------------------------------------------------------------------------
// MFMA flash attention. Q,K bf16 [B,H,S,Dk] (Q pre-scaled); Vt bf16 [B,H,Dk,S].
// 256 thr = 4 waves; wave w owns q rows [q0+w*16, +16). KV tile = 64 keys.
// K tile [key][dk] and Vt tile [d][key] staged via async global_load_lds into
// double-buffered LDS with d-block XOR swizzle (rule #21: linear dest,
// inverse-swizzled global src, swizzled b128 reads -> standard GEMM pattern).
// 2-phase prefetch: vmcnt(0) before the single per-tile barrier.
// fp32 online softmax (16-lane shfl_xor); P via padded per-wave LDS.
// ---------------------------------------------------------------------------
__global__ __launch_bounds__(256) void attn_mfma(const ushort* __restrict__ Q,
                                                 const ushort* __restrict__ K,
                                                 const ushort* __restrict__ Vt,
                                                 ushort* __restrict__ AO)
{
    __shared__ ushort Ks[2][64 * 64];
    __shared__ ushort Vs[2][64 * 64];
    __shared__ ushort Ps[4 * 16 * 72];

    const int tid = threadIdx.x, lane = tid & 63, w = tid >> 6;
    const int li = lane & 15, g = lane >> 4;
    const int b = blockIdx.z, h = blockIdx.y, q0 = blockIdx.x * 64;
    const int bh = b * N_HEADS + h;
    const size_t base = (size_t)bh * SEQ * D_K;    // Q, K
    const size_t vbase = (size_t)bh * D_K * SEQ;   // Vt

    // Q fragments in registers (A-frag: row = lane&15, k = (lane>>4)*8+j)
    const size_t qrow = base + (size_t)(q0 + w * 16 + li) * D_K;
    const short8 qa0 = *(const short8*)&Q[qrow + g * 8];
    const short8 qa1 = *(const short8*)&Q[qrow + 32 + g * 8];

    float m_[4] = {-INFINITY, -INFINITY, -INFINITY, -INFINITY};
    float l_[4] = {0.f, 0.f, 0.f, 0.f};
    f32x4 o[4] = {};

    // staging constants: wave w stages rows [w*16, w*16+16) of each tile,
    // 2 gloads per tile per wave; lane -> row w*16+p*8+(lane>>3), blk lane&7.
    const int srow_l = lane >> 3;   // 0..7
    const int sblk = lane & 7;
    ushort* Pw = &Ps[w * 16 * 72];

    const ushort* Kt0 = &K[base];
    const ushort* Vt0 = &Vt[vbase];

#define STAGE(kt_, buf_)                                                      \
    {                                                                         \
        _Pragma("unroll")                                                     \
        for (int p = 0; p < 2; ++p) {                                         \
            const int row = w * 16 + p * 8 + srow_l;                          \
            const int db = sblk ^ (row & 7);                                  \
            gload_lds16(Kt0 + ((size_t)((kt_) * 64 + row)) * D_K + db * 8,    \
                        &Ks[buf_][(w * 16 + p * 8) * 64]);                    \
            gload_lds16(Vt0 + (size_t)row * SEQ + (kt_) * 64 + db * 8,        \
                        &Vs[buf_][(w * 16 + p * 8) * 64]);                    \
        }                                                                     \
    }

    STAGE(0, 0);

    const int NT = SEQ / 64;
    for (int kt = 0; kt < NT; ++kt) {
        const int cur = kt & 1;
        asm volatile("s_waitcnt vmcnt(0)" ::: "memory");
        __syncthreads();
        if (kt + 1 < NT) STAGE(kt + 1, cur ^ 1);

        // QK^T: S[16 q][64 keys]; B-frag (col=key, k=dk) from swizzled Ks
        f32x4 s4[4];
#pragma unroll
        for (int kf = 0; kf < 4; ++kf) {
            const int row = kf * 16 + li;  // key
            short8 kb0 = *(const short8*)&Ks[cur][row * 64 + ((g ^ (row & 7)) * 8)];
            short8 kb1 = *(const short8*)&Ks[cur][row * 64 + (((4 + g) ^ (row & 7)) * 8)];
            f32x4 z = {0.f, 0.f, 0.f, 0.f};
            z = __builtin_amdgcn_mfma_f32_16x16x32_bf16(qa0, kb0, z, 0, 0, 0);
            z = __builtin_amdgcn_mfma_f32_16x16x32_bf16(qa1, kb1, z, 0, 0, 0);
            s4[kf] = z;
        }

        // online softmax; lane holds rows g*4+r, cols kf*16+li
        float p[4][4];
#pragma unroll
        for (int r = 0; r < 4; ++r) {
            float mx = fmaxf(fmaxf(s4[0][r], s4[1][r]), fmaxf(s4[2][r], s4[3][r]));
#pragma unroll
            for (int off = 1; off < 16; off <<= 1)
                mx = fmaxf(mx, __shfl_xor(mx, off, 64));
            const float mn = fmaxf(m_[r], mx);
            const float scale = __expf(m_[r] - mn);
            float ts = 0.f;
#pragma unroll
            for (int kf = 0; kf < 4; ++kf) {
                const float pe = __expf(s4[kf][r] - mn);
                p[kf][r] = pe; ts += pe;
            }
#pragma unroll
            for (int off = 1; off < 16; off <<= 1)
                ts += __shfl_xor(ts, off, 64);
            l_[r] = l_[r] * scale + ts;
            m_[r] = mn;
#pragma unroll
            for (int df = 0; df < 4; ++df) o[df][r] *= scale;
        }

        // P -> per-wave LDS (bf16), re-fragment for PV
#pragma unroll
        for (int r = 0; r < 4; ++r)
#pragma unroll
            for (int kf = 0; kf < 4; ++kf)
                Pw[(g * 4 + r) * 72 + kf * 16 + li] = f2bf(p[kf][r]);
        asm volatile("s_waitcnt lgkmcnt(0)" ::: "memory");
        __builtin_amdgcn_sched_barrier(0);

        // PV: A-frag from Pw (row=q, k=key); B-frag (col=d, k=key) from Vs
        const short8 pa0 = *(const short8*)&Pw[li * 72 + g * 8];
        const short8 pa1 = *(const short8*)&Pw[li * 72 + 32 + g * 8];
#pragma unroll
        for (int df = 0; df < 4; ++df) {
            const int row = df * 16 + li;  // d
            short8 vb0 = *(const short8*)&Vs[cur][row * 64 + ((g ^ (row & 7)) * 8)];
            short8 vb1 = *(const short8*)&Vs[cur][row * 64 + (((4 + g) ^ (row & 7)) * 8)];
            o[df] = __builtin_amdgcn_mfma_f32_16x16x32_bf16(pa0, vb0, o[df], 0, 0, 0);
            o[df] = __builtin_amdgcn_mfma_f32_16x16x32_bf16(pa1, vb1, o[df], 0, 0, 0);
        }
    }
#undef STAGE

    // normalize, store ao[b][q0+w*16+g*4+r][h*64 + df*16 + li]
    float inv[4];
#pragma unroll
    for (int r = 0; r < 4; ++r) inv[r] = 1.0f / l_[r];
#pragma unroll
    for (int df = 0; df < 4; ++df)
#pragma unroll
        for (int r = 0; r < 4; ++r) {
            const size_t row = (size_t)b * SEQ + q0 + w * 16 + g * 4 + r;
            AO[row * D_MODEL + h * 64 + df * 16 + li] = f2bf(o[df][r] * inv[r]);
        }
}

// ---------------------------------------------------------------------------
extern "C" void kernel_launch(void* const* d_in, const int* in_sizes, int n_in,
                              void* d_out, int out_size, void* d_ws, size_t ws_size,
                              hipStream_t stream)
{
    const float* x  = (const float*)d_in[0];
    const float* Wq = (const float*)d_in[1];
    const float* Wk = (const float*)d_in[2];
    const float* Wv = (const float*)d_in[3];
    const float* Wo = (const float*)d_in[4];
    float* out = (float*)d_out;

    // bf16 workspace layout
    ushort* xb   = (ushort*)d_ws;                       // [4096][1024]
    ushort* Wqkv = xb + (size_t)M_TOTAL * D_MODEL;      // [3072][1024]
    ushort* Wob  = Wqkv + (size_t)3 * D_MODEL * D_MODEL;// [1024][1024]
    ushort* q    = Wob + (size_t)D_MODEL * D_MODEL;     // [B,H,S,Dk]
    ushort* k    = q + (size_t)M_TOTAL * D_MODEL;       // [B,H,S,Dk]
    ushort* vt   = k + (size_t)M_TOTAL * D_MODEL;       // [B,H,Dk,S]
    ushort* ao   = vt + (size_t)M_TOTAL * D_MODEL;      // [B,S,D]

    // fused casts: 4096 (x) + 4*1024 (weights) blocks
    hipLaunchKernelGGL(cast_all, dim3(8192), dim3(256), 0, stream,
                       x, Wq, Wk, Wv, Wo, xb, Wqkv, Wob);

    // fused QKV projection: [4096,1024] @ [3072,1024]^T -> q,k,vt scatter
    hipLaunchKernelGGL((gemm_bf16<1>), dim3(3 * D_MODEL / 128, M_TOTAL / 128), dim3(256),
                       0, stream, xb, Wqkv, q, k, vt, M_TOTAL, 3 * D_MODEL, D_MODEL);

    // flash attention
    hipLaunchKernelGGL(attn_mfma, dim3(SEQ / 64, N_HEADS, BATCH), dim3(256),
                       0, stream, q, k, vt, ao);

    // output projection: [4096,1024] @ [1024,1024]^T -> fp32 out
    hipLaunchKernelGGL((gemm_bf16<0>), dim3(D_MODEL / 128, M_TOTAL / 128), dim3(256),
                       0, stream, ao, Wob, out, (void*)0, (void*)0,
                       M_TOTAL, D_MODEL, D_MODEL);
}

// Round 4
// 191.739 us; speedup vs baseline: 6.7595x; 1.2230x over previous
//
#include <hip/hip_runtime.h>
#include <hip/hip_bf16.h>
#include <math.h>

#define D_MODEL 1024
#define N_HEADS 16
#define D_K     64
#define BATCH   2
#define SEQ     2048
#define M_TOTAL (BATCH * SEQ)   // 4096

typedef __attribute__((ext_vector_type(8))) short short8;   // 8 bf16 = 4 VGPR
typedef __attribute__((ext_vector_type(4))) float f32x4;

__device__ __forceinline__ ushort f2bf(float f) {
    __hip_bfloat16 h = __float2bfloat16(f);
    union { __hip_bfloat16 h; ushort u; } c; c.h = h; return c.u;
}

__device__ __forceinline__ void gload_lds16(const void* g, void* l) {
    __builtin_amdgcn_global_load_lds(
        (const __attribute__((address_space(1))) void*)g,
        (__attribute__((address_space(3))) void*)l, 16, 0, 0);
}

// ---------------------------------------------------------------------------
// Fused f32 -> bf16 cast for all 5 tensors in one launch.
// ---------------------------------------------------------------------------
__global__ __launch_bounds__(256) void cast_all(const float* __restrict__ x,
                                                const float* __restrict__ Wq,
                                                const float* __restrict__ Wk,
                                                const float* __restrict__ Wv,
                                                const float* __restrict__ Wo,
                                                ushort* __restrict__ xb,
                                                ushort* __restrict__ wqkv,
                                                ushort* __restrict__ wob)
{
    const int bi = blockIdx.x;
    const float* src; ushort* dst; int blk;
    const int NW = D_MODEL * D_MODEL;  // 1M
    if (bi < 4096)      { src = x;  dst = xb;            blk = bi; }
    else if (bi < 5120) { src = Wq; dst = wqkv;          blk = bi - 4096; }
    else if (bi < 6144) { src = Wk; dst = wqkv + NW;     blk = bi - 5120; }
    else if (bi < 7168) { src = Wv; dst = wqkv + 2 * NW; blk = bi - 6144; }
    else                { src = Wo; dst = wob;           blk = bi - 7168; }
    const int i = blk * 1024 + threadIdx.x * 4;
    float4 v = *(const float4*)&src[i];
    ushort4 o;
    o.x = f2bf(v.x); o.y = f2bf(v.y); o.z = f2bf(v.z); o.w = f2bf(v.w);
    *(ushort4*)&dst[i] = o;
}

// ---------------------------------------------------------------------------
// bf16 GEMM: C = A(M,K) * B(N,K)^T, fp32 accum via mfma_f32_16x16x32_bf16.
// 128x128 tile, BK=32, 256 thr (4 waves), global_load_lds w=16,
// double-buffered LDS with vmcnt-before-barrier prefetch.
// EPI 0: C fp32 row-major [M][N].
// EPI 1: QKV scatter: q,k bf16 [B,H,S,Dk] (q scaled by 0.125*log2e for the
//        exp2-domain softmax); v bf16 [B,H,Dk,S].
// ---------------------------------------------------------------------------
template <int EPI>
__global__ __launch_bounds__(256) void gemm_bf16(const ushort* __restrict__ A,
                                                 const ushort* __restrict__ B,
                                                 void* __restrict__ C0,
                                                 void* __restrict__ C1,
                                                 void* __restrict__ C2,
                                                 int M, int N, int K)
{
    __shared__ ushort As[2][4 * 128 * 8];
    __shared__ ushort Bs[2][4 * 128 * 8];

    const int tid = threadIdx.x;
    const int lane = tid & 63;
    const int w = tid >> 6;
    const int li = lane & 15;
    const int kg = lane >> 4;
    const int m0 = blockIdx.y * 128;
    const int n0 = blockIdx.x * 128;
    const int wr = (w >> 1) * 64;
    const int wc = (w & 1) * 64;

    f32x4 acc[4][4] = {};

    const int s1 = tid, s2 = tid + 256;
    const ushort* ga1 = &A[(size_t)(m0 + (s1 & 127)) * K + (s1 >> 7) * 8];
    const ushort* ga2 = &A[(size_t)(m0 + (s2 & 127)) * K + (s2 >> 7) * 8];
    const ushort* gb1 = &B[(size_t)(n0 + (s1 & 127)) * K + (s1 >> 7) * 8];
    const ushort* gb2 = &B[(size_t)(n0 + (s2 & 127)) * K + (s2 >> 7) * 8];

    const int NT = K / 32;
    gload_lds16(ga1, &As[0][s1 * 8]);
    gload_lds16(ga2, &As[0][s2 * 8]);
    gload_lds16(gb1, &Bs[0][s1 * 8]);
    gload_lds16(gb2, &Bs[0][s2 * 8]);

    for (int t = 0; t < NT; ++t) {
        const int cur = t & 1;
        asm volatile("s_waitcnt vmcnt(0)" ::: "memory");
        __syncthreads();
        if (t + 1 < NT) {
            const int kb = (t + 1) * 32;
            const int nxt = cur ^ 1;
            gload_lds16(ga1 + kb, &As[nxt][s1 * 8]);
            gload_lds16(ga2 + kb, &As[nxt][s2 * 8]);
            gload_lds16(gb1 + kb, &Bs[nxt][s1 * 8]);
            gload_lds16(gb2 + kb, &Bs[nxt][s2 * 8]);
        }
        short8 af[4], bf_[4];
#pragma unroll
        for (int m = 0; m < 4; ++m)
            af[m] = *(const short8*)&As[cur][(kg * 128 + wr + m * 16 + li) * 8];
#pragma unroll
        for (int n = 0; n < 4; ++n)
            bf_[n] = *(const short8*)&Bs[cur][(kg * 128 + wc + n * 16 + li) * 8];
#pragma unroll
        for (int m = 0; m < 4; ++m)
#pragma unroll
            for (int n = 0; n < 4; ++n)
                acc[m][n] = __builtin_amdgcn_mfma_f32_16x16x32_bf16(
                    af[m], bf_[n], acc[m][n], 0, 0, 0);
    }

    if (EPI == 1) {
        ushort* q = (ushort*)C0; ushort* k = (ushort*)C1; ushort* v = (ushort*)C2;
        const float QSCALE = 0.125f * 1.44269504088896f;   // fold log2(e)
#pragma unroll
        for (int m = 0; m < 4; ++m) {
            const int Rb = m0 + wr + m * 16 + kg * 4;
#pragma unroll
            for (int n = 0; n < 4; ++n) {
                const int Ncol = n0 + wc + n * 16 + li;
                const int proj = Ncol >> 10;
                const int rem = Ncol & 1023;
                const int h = rem >> 6, dk = rem & 63;
#pragma unroll
                for (int r = 0; r < 4; ++r) {
                    const int R = Rb + r;
                    const int b = R >> 11, s = R & 2047;
                    const int bh = b * N_HEADS + h;
                    if (proj == 0)
                        q[((size_t)bh * SEQ + s) * D_K + dk] = f2bf(acc[m][n][r] * QSCALE);
                    else if (proj == 1)
                        k[((size_t)bh * SEQ + s) * D_K + dk] = f2bf(acc[m][n][r]);
                    else  // V stored transposed: [B,H,Dk,S]
                        v[((size_t)bh * D_K + dk) * SEQ + s] = f2bf(acc[m][n][r]);
                }
            }
        }
    } else {
        float* C = (float*)C0;
#pragma unroll
        for (int m = 0; m < 4; ++m) {
            const int Rb = m0 + wr + m * 16 + kg * 4;
#pragma unroll
            for (int n = 0; n < 4; ++n) {
                const int Ncol = n0 + wc + n * 16 + li;
#pragma unroll
                for (int r = 0; r < 4; ++r)
                    C[(size_t)(Rb + r) * N + Ncol] = acc[m][n][r];
            }
        }
    }
}

// ---------------------------------------------------------------------------
// MFMA flash attention, swapped-operand form.
// Q,K bf16 [B,H,S,Dk] (Q pre-scaled by 0.125*log2e); Vt bf16 [B,H,Dk,S].
// 256 thr = 4 waves; wave w owns q rows [q0+w*16, +16). KV tile = 64 keys.
// QK^T computed as mfma(K,Q) -> S^T[key][q]: lane (li,g) holds 16 keys
// (kf*16+g*4+r) for q-row li => row stats are 15 in-reg ops + 2 shfls,
// m/l are lane-local scalars (exp2 domain, defer-max THR=8).
// PV computed as mfma(Vt,P^T) -> O^T[d][q]: rescale/normalize lane-local.
// P round-trip: 8 packed ds_write_b32 -> 2 ds_read_b128 through a
// block-XOR-swizzled per-wave Ps[16][64] (<=2-way banks).
// K/Vt tiles: async global_load_lds, double-buffered, d-block XOR swizzle.
// LDS total 40960 B -> 4 blocks/CU.
// ---------------------------------------------------------------------------
__global__ __launch_bounds__(256) void attn_mfma(const ushort* __restrict__ Q,
                                                 const ushort* __restrict__ K,
                                                 const ushort* __restrict__ Vt,
                                                 ushort* __restrict__ AO)
{
    __shared__ ushort Ks[2][64 * 64];
    __shared__ ushort Vs[2][64 * 64];
    __shared__ ushort Ps[4][16 * 64];

    const int tid = threadIdx.x, lane = tid & 63, w = tid >> 6;
    const int li = lane & 15, g = lane >> 4;
    const int b = blockIdx.z, h = blockIdx.y, q0 = blockIdx.x * 64;
    const int bh = b * N_HEADS + h;
    const size_t base = (size_t)bh * SEQ * D_K;    // Q, K
    const size_t vbase = (size_t)bh * D_K * SEQ;   // Vt

    // Q fragments (B-frag: col=q=li, k=dk=(g)*8+j)
    const size_t qrow = base + (size_t)(q0 + w * 16 + li) * D_K;
    const short8 qa0 = *(const short8*)&Q[qrow + g * 8];
    const short8 qa1 = *(const short8*)&Q[qrow + 32 + g * 8];

    float m_ = -INFINITY, l_ = 0.f;
    f32x4 o[4] = {};   // O^T frags: col=q=li, row d=df*16+g*4+r

    const int srow_l = lane >> 3;   // 0..7
    const int sblk = lane & 7;
    ushort* Pw = &Ps[w][0];
    const ushort* Kt0 = &K[base];
    const ushort* Vt0 = &Vt[vbase];

#define STAGE(kt_, buf_)                                                      \
    {                                                                         \
        _Pragma("unroll")                                                     \
        for (int p = 0; p < 2; ++p) {                                         \
            const int row = w * 16 + p * 8 + srow_l;                          \
            const int db = sblk ^ (row & 7);                                  \
            gload_lds16(Kt0 + ((size_t)((kt_) * 64 + row)) * D_K + db * 8,    \
                        &Ks[buf_][(w * 16 + p * 8) * 64]);                    \
            gload_lds16(Vt0 + (size_t)row * SEQ + (kt_) * 64 + db * 8,        \
                        &Vs[buf_][(w * 16 + p * 8) * 64]);                    \
        }                                                                     \
    }

    STAGE(0, 0);

    const int NT = SEQ / 64;
    for (int kt = 0; kt < NT; ++kt) {
        const int cur = kt & 1;
        asm volatile("s_waitcnt vmcnt(0)" ::: "memory");
        __syncthreads();
        if (kt + 1 < NT) STAGE(kt + 1, cur ^ 1);

        // S^T = mfma(K, Q): s4[kf] holds keys kf*16+g*4+r for q-row li
        f32x4 s4[4];
#pragma unroll
        for (int kf = 0; kf < 4; ++kf) {
            const int row = kf * 16 + li;  // key (A-frag row)
            short8 kb0 = *(const short8*)&Ks[cur][row * 64 + ((g ^ (row & 7)) * 8)];
            short8 kb1 = *(const short8*)&Ks[cur][row * 64 + (((4 + g) ^ (row & 7)) * 8)];
            f32x4 z = {0.f, 0.f, 0.f, 0.f};
            z = __builtin_amdgcn_mfma_f32_16x16x32_bf16(kb0, qa0, z, 0, 0, 0);
            z = __builtin_amdgcn_mfma_f32_16x16x32_bf16(kb1, qa1, z, 0, 0, 0);
            s4[kf] = z;
        }

        // row max: 15 in-reg + 2 shfl (lane-local q-row)
        f32x4 mm01, mm;
#pragma unroll
        for (int e = 0; e < 4; ++e) mm01[e] = fmaxf(s4[0][e], s4[1][e]);
#pragma unroll
        for (int e = 0; e < 4; ++e) mm[e] = fmaxf(mm01[e], fmaxf(s4[2][e], s4[3][e]));
        float mx = fmaxf(fmaxf(mm[0], mm[1]), fmaxf(mm[2], mm[3]));
        mx = fmaxf(mx, __shfl_xor(mx, 16, 64));
        mx = fmaxf(mx, __shfl_xor(mx, 32, 64));

        // defer-max: only rescale when the running max grows by > 8 (log2)
        if (__any(mx > m_ + 8.0f)) {
            const float mn = fmaxf(m_, mx);
            const float sc = exp2f(m_ - mn);
            l_ *= sc;
#pragma unroll
            for (int df = 0; df < 4; ++df)
#pragma unroll
                for (int e = 0; e < 4; ++e) o[df][e] *= sc;
            m_ = mn;
        }

        // p = 2^(s - m), tile sum
        float p[4][4];
        float ts = 0.f;
#pragma unroll
        for (int kf = 0; kf < 4; ++kf)
#pragma unroll
            for (int r = 0; r < 4; ++r) {
                p[kf][r] = exp2f(s4[kf][r] - m_);
                ts += p[kf][r];
            }
        ts += __shfl_xor(ts, 16, 64);
        ts += __shfl_xor(ts, 32, 64);
        l_ += ts;

        // P^T -> Ps[q=li][key], packed pairs, block-XOR swizzle (blocks of 8)
#pragma unroll
        for (int kf = 0; kf < 4; ++kf)
#pragma unroll
            for (int rr = 0; rr < 2; ++rr) {
                const uint u = ((uint)f2bf(p[kf][2 * rr + 1]) << 16) | f2bf(p[kf][2 * rr]);
                const int blk = 2 * kf + (g >> 1);        // key block (8 keys)
                *(uint*)&Pw[li * 64 + ((blk ^ (li & 7)) * 8) + (g & 1) * 4 + rr * 2] = u;
            }
        asm volatile("s_waitcnt lgkmcnt(0)" ::: "memory");
        __builtin_amdgcn_sched_barrier(0);

        // O^T += mfma(Vt, P^T): A=V^T (row=d, k=key), B=P^T (col=q, k=key)
        const short8 pb0 = *(const short8*)&Pw[li * 64 + ((g ^ (li & 7)) * 8)];
        const short8 pb1 = *(const short8*)&Pw[li * 64 + (((4 + g) ^ (li & 7)) * 8)];
#pragma unroll
        for (int df = 0; df < 4; ++df) {
            const int row = df * 16 + li;  // d (A-frag row)
            short8 vb0 = *(const short8*)&Vs[cur][row * 64 + ((g ^ (row & 7)) * 8)];
            short8 vb1 = *(const short8*)&Vs[cur][row * 64 + (((4 + g) ^ (row & 7)) * 8)];
            o[df] = __builtin_amdgcn_mfma_f32_16x16x32_bf16(vb0, pb0, o[df], 0, 0, 0);
            o[df] = __builtin_amdgcn_mfma_f32_16x16x32_bf16(vb1, pb1, o[df], 0, 0, 0);
        }
    }
#undef STAGE

    // normalize (lane-local) and store O[q][d]: d = df*16 + g*4 + r
    const float inv = 1.0f / l_;
    ushort* Ao = &AO[((size_t)b * SEQ + q0 + w * 16 + li) * D_MODEL + h * 64];
#pragma unroll
    for (int df = 0; df < 4; ++df)
#pragma unroll
        for (int rr = 0; rr < 2; ++rr) {
            const uint u = ((uint)f2bf(o[df][2 * rr + 1] * inv) << 16) |
                           f2bf(o[df][2 * rr] * inv);
            *(uint*)&Ao[df * 16 + g * 4 + rr * 2] = u;
        }
}

// ---------------------------------------------------------------------------
extern "C" void kernel_launch(void* const* d_in, const int* in_sizes, int n_in,
                              void* d_out, int out_size, void* d_ws, size_t ws_size,
                              hipStream_t stream)
{
    const float* x  = (const float*)d_in[0];
    const float* Wq = (const float*)d_in[1];
    const float* Wk = (const float*)d_in[2];
    const float* Wv = (const float*)d_in[3];
    const float* Wo = (const float*)d_in[4];
    float* out = (float*)d_out;

    ushort* xb   = (ushort*)d_ws;                       // [4096][1024]
    ushort* Wqkv = xb + (size_t)M_TOTAL * D_MODEL;      // [3072][1024]
    ushort* Wob  = Wqkv + (size_t)3 * D_MODEL * D_MODEL;// [1024][1024]
    ushort* q    = Wob + (size_t)D_MODEL * D_MODEL;     // [B,H,S,Dk]
    ushort* k    = q + (size_t)M_TOTAL * D_MODEL;       // [B,H,S,Dk]
    ushort* vt   = k + (size_t)M_TOTAL * D_MODEL;       // [B,H,Dk,S]
    ushort* ao   = vt + (size_t)M_TOTAL * D_MODEL;      // [B,S,D]

    hipLaunchKernelGGL(cast_all, dim3(8192), dim3(256), 0, stream,
                       x, Wq, Wk, Wv, Wo, xb, Wqkv, Wob);

    hipLaunchKernelGGL((gemm_bf16<1>), dim3(3 * D_MODEL / 128, M_TOTAL / 128), dim3(256),
                       0, stream, xb, Wqkv, q, k, vt, M_TOTAL, 3 * D_MODEL, D_MODEL);

    hipLaunchKernelGGL(attn_mfma, dim3(SEQ / 64, N_HEADS, BATCH), dim3(256),
                       0, stream, q, k, vt, ao);

    hipLaunchKernelGGL((gemm_bf16<0>), dim3(D_MODEL / 128, M_TOTAL / 128), dim3(256),
                       0, stream, ao, Wob, out, (void*)0, (void*)0,
                       M_TOTAL, D_MODEL, D_MODEL);
}

// Round 6
// 187.459 us; speedup vs baseline: 6.9138x; 1.0228x over previous
//
#include <hip/hip_runtime.h>
#include <hip/hip_bf16.h>
#include <math.h>

#define D_MODEL 1024
#define N_HEADS 16
#define D_K     64
#define BATCH   2
#define SEQ     2048
#define M_TOTAL (BATCH * SEQ)   // 4096

typedef __attribute__((ext_vector_type(8))) short short8;    // 8 bf16 = 4 VGPR
typedef __attribute__((ext_vector_type(4))) float f32x4;
typedef __attribute__((ext_vector_type(16))) float f32x16;

__device__ __forceinline__ ushort f2bf(float f) {
    __hip_bfloat16 h = __float2bfloat16(f);
    union { __hip_bfloat16 h; ushort u; } c; c.h = h; return c.u;
}

__device__ __forceinline__ uint packbf(float a, float b) {
    return ((uint)f2bf(b) << 16) | (uint)f2bf(a);
}

__device__ __forceinline__ void gload_lds16(const void* g, void* l) {
    __builtin_amdgcn_global_load_lds(
        (const __attribute__((address_space(1))) void*)g,
        (__attribute__((address_space(3))) void*)l, 16, 0, 0);
}

// v_permlane32_swap_b32 vdst, vsrc exchanges ONE diagonal of half-wave data
// between the two registers; which diagonal (dst-lo<->src-hi vs dst-hi<->
// src-lo) is probed at runtime (see attn_mfma prologue) so the kernel is
// correct under either ISA reading.
__device__ __forceinline__ void plswap(uint& a, uint& b) {
    asm volatile("v_permlane32_swap_b32 %0, %1" : "+v"(a), "+v"(b));
}

// ---------------------------------------------------------------------------
// Fused f32 -> bf16 cast for all 5 tensors in one launch.
// ---------------------------------------------------------------------------
__global__ __launch_bounds__(256) void cast_all(const float* __restrict__ x,
                                                const float* __restrict__ Wq,
                                                const float* __restrict__ Wk,
                                                const float* __restrict__ Wv,
                                                const float* __restrict__ Wo,
                                                ushort* __restrict__ xb,
                                                ushort* __restrict__ wqkv,
                                                ushort* __restrict__ wob)
{
    const int bi = blockIdx.x;
    const float* src; ushort* dst; int blk;
    const int NW = D_MODEL * D_MODEL;  // 1M
    if (bi < 4096)      { src = x;  dst = xb;            blk = bi; }
    else if (bi < 5120) { src = Wq; dst = wqkv;          blk = bi - 4096; }
    else if (bi < 6144) { src = Wk; dst = wqkv + NW;     blk = bi - 5120; }
    else if (bi < 7168) { src = Wv; dst = wqkv + 2 * NW; blk = bi - 6144; }
    else                { src = Wo; dst = wob;           blk = bi - 7168; }
    const int i = blk * 1024 + threadIdx.x * 4;
    float4 v = *(const float4*)&src[i];
    ushort4 o;
    o.x = f2bf(v.x); o.y = f2bf(v.y); o.z = f2bf(v.z); o.w = f2bf(v.w);
    *(ushort4*)&dst[i] = o;
}

// ---------------------------------------------------------------------------
// bf16 GEMM: C = A(M,K) * B(N,K)^T, fp32 accum via mfma_f32_16x16x32_bf16.
// 128x128 tile, BK=32, 256 thr (4 waves), global_load_lds w=16,
// double-buffered LDS with vmcnt-before-barrier prefetch.
// EPI 0: C fp32 row-major [M][N].
// EPI 1: QKV scatter: q,k bf16 [B,H,S,Dk] (q scaled by 0.125*log2e for the
//        exp2-domain softmax); v bf16 [B,H,Dk,S].
// ---------------------------------------------------------------------------
template <int EPI>
__global__ __launch_bounds__(256) void gemm_bf16(const ushort* __restrict__ A,
                                                 const ushort* __restrict__ B,
                                                 void* __restrict__ C0,
                                                 void* __restrict__ C1,
                                                 void* __restrict__ C2,
                                                 int M, int N, int K)
{
    __shared__ ushort As[2][4 * 128 * 8];
    __shared__ ushort Bs[2][4 * 128 * 8];

    const int tid = threadIdx.x;
    const int lane = tid & 63;
    const int w = tid >> 6;
    const int li = lane & 15;
    const int kg = lane >> 4;
    const int m0 = blockIdx.y * 128;
    const int n0 = blockIdx.x * 128;
    const int wr = (w >> 1) * 64;
    const int wc = (w & 1) * 64;

    f32x4 acc[4][4] = {};

    const int s1 = tid, s2 = tid + 256;
    const ushort* ga1 = &A[(size_t)(m0 + (s1 & 127)) * K + (s1 >> 7) * 8];
    const ushort* ga2 = &A[(size_t)(m0 + (s2 & 127)) * K + (s2 >> 7) * 8];
    const ushort* gb1 = &B[(size_t)(n0 + (s1 & 127)) * K + (s1 >> 7) * 8];
    const ushort* gb2 = &B[(size_t)(n0 + (s2 & 127)) * K + (s2 >> 7) * 8];

    const int NT = K / 32;
    gload_lds16(ga1, &As[0][s1 * 8]);
    gload_lds16(ga2, &As[0][s2 * 8]);
    gload_lds16(gb1, &Bs[0][s1 * 8]);
    gload_lds16(gb2, &Bs[0][s2 * 8]);

    for (int t = 0; t < NT; ++t) {
        const int cur = t & 1;
        asm volatile("s_waitcnt vmcnt(0)" ::: "memory");
        __syncthreads();
        if (t + 1 < NT) {
            const int kb = (t + 1) * 32;
            const int nxt = cur ^ 1;
            gload_lds16(ga1 + kb, &As[nxt][s1 * 8]);
            gload_lds16(ga2 + kb, &As[nxt][s2 * 8]);
            gload_lds16(gb1 + kb, &Bs[nxt][s1 * 8]);
            gload_lds16(gb2 + kb, &Bs[nxt][s2 * 8]);
        }
        short8 af[4], bf_[4];
#pragma unroll
        for (int m = 0; m < 4; ++m)
            af[m] = *(const short8*)&As[cur][(kg * 128 + wr + m * 16 + li) * 8];
#pragma unroll
        for (int n = 0; n < 4; ++n)
            bf_[n] = *(const short8*)&Bs[cur][(kg * 128 + wc + n * 16 + li) * 8];
#pragma unroll
        for (int m = 0; m < 4; ++m)
#pragma unroll
            for (int n = 0; n < 4; ++n)
                acc[m][n] = __builtin_amdgcn_mfma_f32_16x16x32_bf16(
                    af[m], bf_[n], acc[m][n], 0, 0, 0);
    }

    if (EPI == 1) {
        ushort* q = (ushort*)C0; ushort* k = (ushort*)C1; ushort* v = (ushort*)C2;
        const float QSCALE = 0.125f * 1.44269504088896f;   // fold log2(e)
#pragma unroll
        for (int m = 0; m < 4; ++m) {
            const int Rb = m0 + wr + m * 16 + kg * 4;
#pragma unroll
            for (int n = 0; n < 4; ++n) {
                const int Ncol = n0 + wc + n * 16 + li;
                const int proj = Ncol >> 10;
                const int rem = Ncol & 1023;
                const int h = rem >> 6, dk = rem & 63;
#pragma unroll
                for (int r = 0; r < 4; ++r) {
                    const int R = Rb + r;
                    const int b = R >> 11, s = R & 2047;
                    const int bh = b * N_HEADS + h;
                    if (proj == 0)
                        q[((size_t)bh * SEQ + s) * D_K + dk] = f2bf(acc[m][n][r] * QSCALE);
                    else if (proj == 1)
                        k[((size_t)bh * SEQ + s) * D_K + dk] = f2bf(acc[m][n][r]);
                    else  // V stored transposed: [B,H,Dk,S]
                        v[((size_t)bh * D_K + dk) * SEQ + s] = f2bf(acc[m][n][r]);
                }
            }
        }
    } else {
        float* C = (float*)C0;
#pragma unroll
        for (int m = 0; m < 4; ++m) {
            const int Rb = m0 + wr + m * 16 + kg * 4;
#pragma unroll
            for (int n = 0; n < 4; ++n) {
                const int Ncol = n0 + wc + n * 16 + li;
#pragma unroll
                for (int r = 0; r < 4; ++r)
                    C[(size_t)(Rb + r) * N + Ncol] = acc[m][n][r];
            }
        }
    }
}

// ---------------------------------------------------------------------------
// MFMA flash attention, 32x32 swapped-operand form, zero-LDS softmax.
// Q,K bf16 [B,H,S,Dk] (Q pre-scaled by 0.125*log2e); Vt bf16 [B,H,Dk,S].
// 256 thr = 4 waves; wave w owns q rows [q0+w*32, +32). KV tile = 64 keys.
// QK^T = mfma32(K,Q) -> S^T[key][q]: col=q=lane&31; lane + lane^32 hold all
// 64 keys of one q-row => max/sum = 31 in-reg ops + 1 shfl_xor(32).
// P -> PV B-frags in-register via v_permlane32_swap_b32; the exchange
// diagonal is probed at runtime so either ISA semantics yields x=frag_lo,
// y=frag_hi after the correctly-ordered call.
// PV = mfma32(Vt,P^T) -> O^T[d][q], normalize lane-local.
// K/Vt: async global_load_lds, double-buffered, d-block XOR swizzle.
// LDS 32 KiB/block.
// ---------------------------------------------------------------------------
__global__ __launch_bounds__(256) void attn_mfma(const ushort* __restrict__ Q,
                                                 const ushort* __restrict__ K,
                                                 const ushort* __restrict__ Vt,
                                                 ushort* __restrict__ AO)
{
    __shared__ ushort Ks[2][64 * 64];
    __shared__ ushort Vs[2][64 * 64];

    const int tid = threadIdx.x, lane = tid & 63, w = tid >> 6;
    const int r31 = lane & 31, hi = lane >> 5;
    const int b = blockIdx.z, h = blockIdx.y, q0 = blockIdx.x * 128;
    const int bh = b * N_HEADS + h;
    const size_t base = (size_t)bh * SEQ * D_K;    // Q, K
    const size_t vbase = (size_t)bh * D_K * SEQ;   // Vt

    // --- probe the permlane32_swap diagonal (wave-uniform) ---
    uint pa = (uint)lane, pbv = 1000u + (uint)lane;
    plswap(pa, pbv);
    // S_lower (dst-lo <-> src-hi): lane0's pa becomes 1032 -> swap_lo = true
    // S_upper (dst-hi <-> src-lo): lane0's pa stays 0      -> swap_lo = false
    const bool swap_lo = (__builtin_amdgcn_readfirstlane(pa) > 500u);

    // Q B-frags: col=q=r31, k(dk) = ks*16 + hi*8 + j
    const size_t qrow = base + (size_t)(q0 + w * 32 + r31) * D_K;
    short8 qb[4];
#pragma unroll
    for (int ks = 0; ks < 4; ++ks)
        qb[ks] = *(const short8*)&Q[qrow + ks * 16 + hi * 8];

    float m_ = -INFINITY, l_ = 0.f;
    f32x16 o0 = {}, o1 = {};   // O^T: col=q=r31, d = dh*32 + 8*(reg>>2)+4*hi+(reg&3)

    const int srow_l = lane >> 3;   // 0..7
    const int sblk = lane & 7;
    const ushort* Kt0 = &K[base];
    const ushort* Vt0 = &Vt[vbase];

#define STAGE(kt_, buf_)                                                      \
    {                                                                         \
        _Pragma("unroll")                                                     \
        for (int p = 0; p < 2; ++p) {                                         \
            const int row = w * 16 + p * 8 + srow_l;                          \
            const int db = sblk ^ (row & 7);                                  \
            gload_lds16(Kt0 + ((size_t)((kt_) * 64 + row)) * D_K + db * 8,    \
                        &Ks[buf_][(w * 16 + p * 8) * 64]);                    \
            gload_lds16(Vt0 + (size_t)row * SEQ + (kt_) * 64 + db * 8,        \
                        &Vs[buf_][(w * 16 + p * 8) * 64]);                    \
        }                                                                     \
    }

    STAGE(0, 0);

    const int NT = SEQ / 64;
    for (int kt = 0; kt < NT; ++kt) {
        const int cur = kt & 1;
        asm volatile("s_waitcnt vmcnt(0)" ::: "memory");
        __syncthreads();
        if (kt + 1 < NT) STAGE(kt + 1, cur ^ 1);

        // S^T = mfma32(K, Q): s0 = keys 0..31, s1 = keys 32..63 (this tile)
        f32x16 s0 = {}, s1 = {};
#pragma unroll
        for (int ks = 0; ks < 4; ++ks) {
            const int row = r31;   // key (A-frag row), half 0
            short8 kb = *(const short8*)&Ks[cur][row * 64 + (((2 * ks + hi) ^ (row & 7)) * 8)];
            s0 = __builtin_amdgcn_mfma_f32_32x32x16_bf16(kb, qb[ks], s0, 0, 0, 0);
        }
#pragma unroll
        for (int ks = 0; ks < 4; ++ks) {
            const int row = 32 + r31;  // key half 1
            short8 kb = *(const short8*)&Ks[cur][row * 64 + (((2 * ks + hi) ^ (row & 7)) * 8)];
            s1 = __builtin_amdgcn_mfma_f32_32x32x16_bf16(kb, qb[ks], s1, 0, 0, 0);
        }

        // lane-local row max (31 ops) + 1 shfl across the lane^32 partner
        float mx = fmaxf(s0[0], s0[1]);
#pragma unroll
        for (int e = 2; e < 16; ++e) mx = fmaxf(mx, s0[e]);
#pragma unroll
        for (int e = 0; e < 16; ++e) mx = fmaxf(mx, s1[e]);
        mx = fmaxf(mx, __shfl_xor(mx, 32, 64));

        // defer-max: rescale only when the running max grows by > 8 (log2)
        if (__any(mx > m_ + 8.0f)) {
            const float mn = fmaxf(m_, mx);
            const float sc = exp2f(m_ - mn);
            l_ *= sc;
#pragma unroll
            for (int e = 0; e < 16; ++e) { o0[e] *= sc; o1[e] *= sc; }
            m_ = mn;
        }

        // p = 2^(s - m), tile sum (lane-local + 1 shfl)
        f32x16 p0, p1;
        float ts = 0.f;
#pragma unroll
        for (int e = 0; e < 16; ++e) { p0[e] = exp2f(s0[e] - m_); ts += p0[e]; }
#pragma unroll
        for (int e = 0; e < 16; ++e) { p1[e] = exp2f(s1[e] - m_); ts += p1[e]; }
        ts += __shfl_xor(ts, 32, 64);
        l_ += ts;

        // pack p into bf16-pair dwords: u[t] = this lane's 4 keys of key-octet
        // t (keys 8t + 4*hi + 0..3), t = half*4 + rq
        uint u[8][2];
#pragma unroll
        for (int rq = 0; rq < 4; ++rq) {
            u[rq][0]     = packbf(p0[4 * rq + 0], p0[4 * rq + 1]);
            u[rq][1]     = packbf(p0[4 * rq + 2], p0[4 * rq + 3]);
            u[4 + rq][0] = packbf(p1[4 * rq + 0], p1[4 * rq + 1]);
            u[4 + rq][1] = packbf(p1[4 * rq + 2], p1[4 * rq + 3]);
        }

        // per k-slice ks: B-frag needs keys ks*16 + hi*8 + 0..7 = octet 2ks+hi.
        // x = u[2ks] (octet 2ks), y = u[2ks+1]. After the correctly-ordered
        // permlane32_swap (probed), x = frag_lo (j=0..3), y = frag_hi (j=4..7)
        // on BOTH lane halves.
        short8 pb[4];
#pragma unroll
        for (int ks = 0; ks < 4; ++ks) {
            uint x0 = u[2 * ks][0], x1 = u[2 * ks][1];
            uint y0 = u[2 * ks + 1][0], y1 = u[2 * ks + 1][1];
            if (swap_lo) { plswap(y0, x0); plswap(y1, x1); }
            else         { plswap(x0, y0); plswap(x1, y1); }
            union { uint u4[4]; short8 s; } pu;
            pu.u4[0] = x0; pu.u4[1] = x1; pu.u4[2] = y0; pu.u4[3] = y1;
            pb[ks] = pu.s;
        }

        // O^T += mfma32(Vt, P^T): d half 0 then half 1
#pragma unroll
        for (int ks = 0; ks < 4; ++ks) {
            const int row = r31;   // d half 0
            short8 vb = *(const short8*)&Vs[cur][row * 64 + (((2 * ks + hi) ^ (row & 7)) * 8)];
            o0 = __builtin_amdgcn_mfma_f32_32x32x16_bf16(vb, pb[ks], o0, 0, 0, 0);
        }
#pragma unroll
        for (int ks = 0; ks < 4; ++ks) {
            const int row = 32 + r31;  // d half 1
            short8 vb = *(const short8*)&Vs[cur][row * 64 + (((2 * ks + hi) ^ (row & 7)) * 8)];
            o1 = __builtin_amdgcn_mfma_f32_32x32x16_bf16(vb, pb[ks], o1, 0, 0, 0);
        }
    }
#undef STAGE

    // normalize (lane-local q) and store O[q][d], d = 32*dh + 8*rq + 4*hi + e
    const float inv = 1.0f / l_;
    ushort* Ao = &AO[((size_t)b * SEQ + q0 + w * 32 + r31) * D_MODEL + h * 64];
#pragma unroll
    for (int rq = 0; rq < 4; ++rq) {
        uint2 v0, v1;
        v0.x = packbf(o0[4 * rq + 0] * inv, o0[4 * rq + 1] * inv);
        v0.y = packbf(o0[4 * rq + 2] * inv, o0[4 * rq + 3] * inv);
        v1.x = packbf(o1[4 * rq + 0] * inv, o1[4 * rq + 1] * inv);
        v1.y = packbf(o1[4 * rq + 2] * inv, o1[4 * rq + 3] * inv);
        *(uint2*)&Ao[8 * rq + 4 * hi]      = v0;
        *(uint2*)&Ao[32 + 8 * rq + 4 * hi] = v1;
    }
}

// ---------------------------------------------------------------------------
extern "C" void kernel_launch(void* const* d_in, const int* in_sizes, int n_in,
                              void* d_out, int out_size, void* d_ws, size_t ws_size,
                              hipStream_t stream)
{
    const float* x  = (const float*)d_in[0];
    const float* Wq = (const float*)d_in[1];
    const float* Wk = (const float*)d_in[2];
    const float* Wv = (const float*)d_in[3];
    const float* Wo = (const float*)d_in[4];
    float* out = (float*)d_out;

    ushort* xb   = (ushort*)d_ws;                       // [4096][1024]
    ushort* Wqkv = xb + (size_t)M_TOTAL * D_MODEL;      // [3072][1024]
    ushort* Wob  = Wqkv + (size_t)3 * D_MODEL * D_MODEL;// [1024][1024]
    ushort* q    = Wob + (size_t)D_MODEL * D_MODEL;     // [B,H,S,Dk]
    ushort* k    = q + (size_t)M_TOTAL * D_MODEL;       // [B,H,S,Dk]
    ushort* vt   = k + (size_t)M_TOTAL * D_MODEL;       // [B,H,Dk,S]
    ushort* ao   = vt + (size_t)M_TOTAL * D_MODEL;      // [B,S,D]

    hipLaunchKernelGGL(cast_all, dim3(8192), dim3(256), 0, stream,
                       x, Wq, Wk, Wv, Wo, xb, Wqkv, Wob);

    hipLaunchKernelGGL((gemm_bf16<1>), dim3(3 * D_MODEL / 128, M_TOTAL / 128), dim3(256),
                       0, stream, xb, Wqkv, q, k, vt, M_TOTAL, 3 * D_MODEL, D_MODEL);

    hipLaunchKernelGGL(attn_mfma, dim3(SEQ / 128, N_HEADS, BATCH), dim3(256),
                       0, stream, q, k, vt, ao);

    hipLaunchKernelGGL((gemm_bf16<0>), dim3(D_MODEL / 128, M_TOTAL / 128), dim3(256),
                       0, stream, ao, Wob, out, (void*)0, (void*)0,
                       M_TOTAL, D_MODEL, D_MODEL);
}

// Round 7
// 169.905 us; speedup vs baseline: 7.6281x; 1.1033x over previous
//
#include <hip/hip_runtime.h>
#include <hip/hip_bf16.h>
#include <math.h>

#define D_MODEL 1024
#define N_HEADS 16
#define D_K     64
#define BATCH   2
#define SEQ     2048
#define M_TOTAL (BATCH * SEQ)   // 4096

typedef __attribute__((ext_vector_type(8))) short short8;    // 8 bf16 = 4 VGPR
typedef __attribute__((ext_vector_type(4))) float f32x4;
typedef __attribute__((ext_vector_type(16))) float f32x16;

__device__ __forceinline__ ushort f2bf(float f) {
    __hip_bfloat16 h = __float2bfloat16(f);
    union { __hip_bfloat16 h; ushort u; } c; c.h = h; return c.u;
}

__device__ __forceinline__ uint packbf(float a, float b) {
    return ((uint)f2bf(b) << 16) | (uint)f2bf(a);
}

// packed bf16 convert (RNE on gfx950): lo = cvt(a), hi = cvt(b)
__device__ __forceinline__ uint cvtpk(float a, float b) {
    uint r;
    asm("v_cvt_pk_bf16_f32 %0, %1, %2" : "=v"(r) : "v"(a), "v"(b));
    return r;
}

__device__ __forceinline__ void gload_lds16(const void* g, void* l) {
    __builtin_amdgcn_global_load_lds(
        (const __attribute__((address_space(1))) void*)g,
        (__attribute__((address_space(3))) void*)l, 16, 0, 0);
}

// v_permlane32_swap_b32 vdst, vsrc — exchange diagonal probed at runtime.
__device__ __forceinline__ void plswap(uint& a, uint& b) {
    asm volatile("v_permlane32_swap_b32 %0, %1" : "+v"(a), "+v"(b));
}

// ---------------------------------------------------------------------------
// Fused f32 -> bf16 cast for all 5 tensors in one launch.
// ---------------------------------------------------------------------------
__global__ __launch_bounds__(256) void cast_all(const float* __restrict__ x,
                                                const float* __restrict__ Wq,
                                                const float* __restrict__ Wk,
                                                const float* __restrict__ Wv,
                                                const float* __restrict__ Wo,
                                                ushort* __restrict__ xb,
                                                ushort* __restrict__ wqkv,
                                                ushort* __restrict__ wob)
{
    const int bi = blockIdx.x;
    const float* src; ushort* dst; int blk;
    const int NW = D_MODEL * D_MODEL;  // 1M
    if (bi < 4096)      { src = x;  dst = xb;            blk = bi; }
    else if (bi < 5120) { src = Wq; dst = wqkv;          blk = bi - 4096; }
    else if (bi < 6144) { src = Wk; dst = wqkv + NW;     blk = bi - 5120; }
    else if (bi < 7168) { src = Wv; dst = wqkv + 2 * NW; blk = bi - 6144; }
    else                { src = Wo; dst = wob;           blk = bi - 7168; }
    const int i = blk * 1024 + threadIdx.x * 4;
    float4 v = *(const float4*)&src[i];
    ushort4 o;
    o.x = f2bf(v.x); o.y = f2bf(v.y); o.z = f2bf(v.z); o.w = f2bf(v.w);
    *(ushort4*)&dst[i] = o;
}

// ---------------------------------------------------------------------------
// bf16 GEMM: C = A(M,K) * B(N,K)^T, fp32 accum via mfma_f32_16x16x32_bf16.
// 128x128 tile, BK=32, 256 thr (4 waves), global_load_lds w=16,
// double-buffered LDS with vmcnt-before-barrier prefetch.
// EPI 0: C fp32 row-major [M][N].
// EPI 1: QKV scatter: q,k bf16 [B,H,S,Dk] (q scaled by 0.125*log2e for the
//        exp2-domain softmax); v bf16 [B,H,Dk,S].
// ---------------------------------------------------------------------------
template <int EPI>
__global__ __launch_bounds__(256) void gemm_bf16(const ushort* __restrict__ A,
                                                 const ushort* __restrict__ B,
                                                 void* __restrict__ C0,
                                                 void* __restrict__ C1,
                                                 void* __restrict__ C2,
                                                 int M, int N, int K)
{
    __shared__ ushort As[2][4 * 128 * 8];
    __shared__ ushort Bs[2][4 * 128 * 8];

    const int tid = threadIdx.x;
    const int lane = tid & 63;
    const int w = tid >> 6;
    const int li = lane & 15;
    const int kg = lane >> 4;
    const int m0 = blockIdx.y * 128;
    const int n0 = blockIdx.x * 128;
    const int wr = (w >> 1) * 64;
    const int wc = (w & 1) * 64;

    f32x4 acc[4][4] = {};

    const int s1 = tid, s2 = tid + 256;
    const ushort* ga1 = &A[(size_t)(m0 + (s1 & 127)) * K + (s1 >> 7) * 8];
    const ushort* ga2 = &A[(size_t)(m0 + (s2 & 127)) * K + (s2 >> 7) * 8];
    const ushort* gb1 = &B[(size_t)(n0 + (s1 & 127)) * K + (s1 >> 7) * 8];
    const ushort* gb2 = &B[(size_t)(n0 + (s2 & 127)) * K + (s2 >> 7) * 8];

    const int NT = K / 32;
    gload_lds16(ga1, &As[0][s1 * 8]);
    gload_lds16(ga2, &As[0][s2 * 8]);
    gload_lds16(gb1, &Bs[0][s1 * 8]);
    gload_lds16(gb2, &Bs[0][s2 * 8]);

    for (int t = 0; t < NT; ++t) {
        const int cur = t & 1;
        asm volatile("s_waitcnt vmcnt(0)" ::: "memory");
        __syncthreads();
        if (t + 1 < NT) {
            const int kb = (t + 1) * 32;
            const int nxt = cur ^ 1;
            gload_lds16(ga1 + kb, &As[nxt][s1 * 8]);
            gload_lds16(ga2 + kb, &As[nxt][s2 * 8]);
            gload_lds16(gb1 + kb, &Bs[nxt][s1 * 8]);
            gload_lds16(gb2 + kb, &Bs[nxt][s2 * 8]);
        }
        short8 af[4], bf_[4];
#pragma unroll
        for (int m = 0; m < 4; ++m)
            af[m] = *(const short8*)&As[cur][(kg * 128 + wr + m * 16 + li) * 8];
#pragma unroll
        for (int n = 0; n < 4; ++n)
            bf_[n] = *(const short8*)&Bs[cur][(kg * 128 + wc + n * 16 + li) * 8];
#pragma unroll
        for (int m = 0; m < 4; ++m)
#pragma unroll
            for (int n = 0; n < 4; ++n)
                acc[m][n] = __builtin_amdgcn_mfma_f32_16x16x32_bf16(
                    af[m], bf_[n], acc[m][n], 0, 0, 0);
    }

    if (EPI == 1) {
        ushort* q = (ushort*)C0; ushort* k = (ushort*)C1; ushort* v = (ushort*)C2;
        const float QSCALE = 0.125f * 1.44269504088896f;   // fold log2(e)
#pragma unroll
        for (int m = 0; m < 4; ++m) {
            const int Rb = m0 + wr + m * 16 + kg * 4;
#pragma unroll
            for (int n = 0; n < 4; ++n) {
                const int Ncol = n0 + wc + n * 16 + li;
                const int proj = Ncol >> 10;
                const int rem = Ncol & 1023;
                const int h = rem >> 6, dk = rem & 63;
#pragma unroll
                for (int r = 0; r < 4; ++r) {
                    const int R = Rb + r;
                    const int b = R >> 11, s = R & 2047;
                    const int bh = b * N_HEADS + h;
                    if (proj == 0)
                        q[((size_t)bh * SEQ + s) * D_K + dk] = f2bf(acc[m][n][r] * QSCALE);
                    else if (proj == 1)
                        k[((size_t)bh * SEQ + s) * D_K + dk] = f2bf(acc[m][n][r]);
                    else  // V stored transposed: [B,H,Dk,S]
                        v[((size_t)bh * D_K + dk) * SEQ + s] = f2bf(acc[m][n][r]);
                }
            }
        }
    } else {
        float* C = (float*)C0;
#pragma unroll
        for (int m = 0; m < 4; ++m) {
            const int Rb = m0 + wr + m * 16 + kg * 4;
#pragma unroll
            for (int n = 0; n < 4; ++n) {
                const int Ncol = n0 + wc + n * 16 + li;
#pragma unroll
                for (int r = 0; r < 4; ++r)
                    C[(size_t)(Rb + r) * N + Ncol] = acc[m][n][r];
            }
        }
    }
}

// ---------------------------------------------------------------------------
// MFMA flash attention, 32x32 swapped form, in-block KV-split (8 waves).
// Q,K bf16 [B,H,S,Dk] (Q pre-scaled by 0.125*log2e); Vt bf16 [B,H,Dk,S].
// 512 thr = 8 waves: wave = (kvh, wq); wq owns q rows [q0+wq*32, +32),
// kvh owns KV tiles [16*kvh, 16*kvh+16). Each kvh group has its own
// double-buffered K/V LDS stream (64 KiB total -> 2 blocks/CU, 4 waves/SIMD).
// Per-group flash loop identical to R6 (zero-LDS softmax, permlane P-swap,
// probed diagonal). At the end, group 1 dumps (o,m,l) to LDS (aliasing the
// staging pool, post-barrier) and group 0 merges + stores.
// ---------------------------------------------------------------------------
__global__ __launch_bounds__(512, 4) void attn_mfma(const ushort* __restrict__ Q,
                                                    const ushort* __restrict__ K,
                                                    const ushort* __restrict__ Vt,
                                                    ushort* __restrict__ AO)
{
    __shared__ ushort pool[2][2][2][64 * 64];   // [stream kvh][K/V][buf][8KB]

    const int tid = threadIdx.x, lane = tid & 63, w = tid >> 6;
    const int wq = w & 3, kvh = w >> 2;
    const int r31 = lane & 31, hi = lane >> 5;
    const int b = blockIdx.z, h = blockIdx.y, q0 = blockIdx.x * 128;
    const int bh = b * N_HEADS + h;
    const size_t base = (size_t)bh * SEQ * D_K;    // Q, K
    const size_t vbase = (size_t)bh * D_K * SEQ;   // Vt

    // --- probe the permlane32_swap diagonal (wave-uniform) ---
    uint pa = (uint)lane, pbv = 1000u + (uint)lane;
    plswap(pa, pbv);
    const bool swap_lo = (__builtin_amdgcn_readfirstlane(pa) > 500u);

    // Q B-frags: col=q=r31, k(dk) = ks*16 + hi*8 + j
    const size_t qrow = base + (size_t)(q0 + wq * 32 + r31) * D_K;
    short8 qb[4];
#pragma unroll
    for (int ks = 0; ks < 4; ++ks)
        qb[ks] = *(const short8*)&Q[qrow + ks * 16 + hi * 8];

    float m_ = -INFINITY, l_ = 0.f;
    f32x16 o0 = {}, o1 = {};   // O^T: col=q=r31, d = dh*32 + 8*(reg>>2)+4*hi+(reg&3)

    const int srow_l = lane >> 3;   // 0..7
    const int sblk = lane & 7;
    const ushort* Kt0 = &K[base];
    const ushort* Vt0 = &Vt[vbase];
    const int tile0 = kvh * 16;     // this group's first KV tile

    // hoisted lane-constant LDS read offsets (elements):
    // off[half][ks] = (half*32+r31)*64 + (((2ks+hi) ^ (r31&7)) * 8)
    const int xr = r31 & 7;
    int off[2][4];
#pragma unroll
    for (int hf = 0; hf < 2; ++hf)
#pragma unroll
        for (int ks = 0; ks < 4; ++ks)
            off[hf][ks] = hf * 2048 + r31 * 64 + (((2 * ks + hi) ^ xr) * 8);

    const ushort* Kst = &pool[kvh][0][0][0];
    const ushort* Vst = &pool[kvh][1][0][0];

#define STAGE(kt_, buf_)                                                       \
    {                                                                          \
        _Pragma("unroll")                                                      \
        for (int p = 0; p < 2; ++p) {                                          \
            const int row = wq * 16 + p * 8 + srow_l;                          \
            const int db = sblk ^ (row & 7);                                   \
            gload_lds16(Kt0 + ((size_t)((tile0 + (kt_)) * 64 + row)) * D_K + db * 8, \
                        &pool[kvh][0][buf_][(wq * 16 + p * 8) * 64]);          \
            gload_lds16(Vt0 + (size_t)row * SEQ + (tile0 + (kt_)) * 64 + db * 8,     \
                        &pool[kvh][1][buf_][(wq * 16 + p * 8) * 64]);          \
        }                                                                      \
    }

    STAGE(0, 0);

    const int NT = SEQ / 64 / 2;    // 16 tiles per group
    for (int kt = 0; kt < NT; ++kt) {
        const int cur = kt & 1;
        asm volatile("s_waitcnt vmcnt(0)" ::: "memory");
        __syncthreads();
        if (kt + 1 < NT) STAGE(kt + 1, cur ^ 1);
        const int cb = cur * 4096;

        // S^T = mfma32(K, Q)
        f32x16 s0 = {}, s1 = {};
        __builtin_amdgcn_s_setprio(1);
#pragma unroll
        for (int ks = 0; ks < 4; ++ks) {
            short8 kb = *(const short8*)(Kst + cb + off[0][ks]);
            s0 = __builtin_amdgcn_mfma_f32_32x32x16_bf16(kb, qb[ks], s0, 0, 0, 0);
        }
#pragma unroll
        for (int ks = 0; ks < 4; ++ks) {
            short8 kb = *(const short8*)(Kst + cb + off[1][ks]);
            s1 = __builtin_amdgcn_mfma_f32_32x32x16_bf16(kb, qb[ks], s1, 0, 0, 0);
        }
        __builtin_amdgcn_s_setprio(0);

        // lane-local row max (31 ops) + 1 shfl across the lane^32 partner
        float mx = fmaxf(s0[0], s0[1]);
#pragma unroll
        for (int e = 2; e < 16; ++e) mx = fmaxf(mx, s0[e]);
#pragma unroll
        for (int e = 0; e < 16; ++e) mx = fmaxf(mx, s1[e]);
        mx = fmaxf(mx, __shfl_xor(mx, 32, 64));

        // defer-max: rescale only when the running max grows by > 8 (log2)
        if (__any(mx > m_ + 8.0f)) {
            const float mn = fmaxf(m_, mx);
            const float sc = exp2f(m_ - mn);
            l_ *= sc;
#pragma unroll
            for (int e = 0; e < 16; ++e) { o0[e] *= sc; o1[e] *= sc; }
            m_ = mn;
        }

        // p = 2^(s - m), tile sum (lane-local + 1 shfl)
        f32x16 p0, p1;
        float ts = 0.f;
#pragma unroll
        for (int e = 0; e < 16; ++e) { p0[e] = exp2f(s0[e] - m_); ts += p0[e]; }
#pragma unroll
        for (int e = 0; e < 16; ++e) { p1[e] = exp2f(s1[e] - m_); ts += p1[e]; }
        ts += __shfl_xor(ts, 32, 64);
        l_ += ts;

        // pack p into bf16-pair dwords (v_cvt_pk_bf16_f32)
        uint u[8][2];
#pragma unroll
        for (int rq = 0; rq < 4; ++rq) {
            u[rq][0]     = cvtpk(p0[4 * rq + 0], p0[4 * rq + 1]);
            u[rq][1]     = cvtpk(p0[4 * rq + 2], p0[4 * rq + 3]);
            u[4 + rq][0] = cvtpk(p1[4 * rq + 0], p1[4 * rq + 1]);
            u[4 + rq][1] = cvtpk(p1[4 * rq + 2], p1[4 * rq + 3]);
        }

        // per k-slice: B-frag = keys octet 2ks (x) + octet 2ks+1 (y), swapped
        short8 pb[4];
#pragma unroll
        for (int ks = 0; ks < 4; ++ks) {
            uint x0 = u[2 * ks][0], x1 = u[2 * ks][1];
            uint y0 = u[2 * ks + 1][0], y1 = u[2 * ks + 1][1];
            if (swap_lo) { plswap(y0, x0); plswap(y1, x1); }
            else         { plswap(x0, y0); plswap(x1, y1); }
            union { uint u4[4]; short8 s; } pu;
            pu.u4[0] = x0; pu.u4[1] = x1; pu.u4[2] = y0; pu.u4[3] = y1;
            pb[ks] = pu.s;
        }

        // O^T += mfma32(Vt, P^T)
        __builtin_amdgcn_s_setprio(1);
#pragma unroll
        for (int ks = 0; ks < 4; ++ks) {
            short8 vb = *(const short8*)(Vst + cb + off[0][ks]);
            o0 = __builtin_amdgcn_mfma_f32_32x32x16_bf16(vb, pb[ks], o0, 0, 0, 0);
        }
#pragma unroll
        for (int ks = 0; ks < 4; ++ks) {
            short8 vb = *(const short8*)(Vst + cb + off[1][ks]);
            o1 = __builtin_amdgcn_mfma_f32_32x32x16_bf16(vb, pb[ks], o1, 0, 0, 0);
        }
        __builtin_amdgcn_s_setprio(0);
    }
#undef STAGE

    // ---- merge the two KV halves through LDS (alias the staging pool) ----
    __syncthreads();
    float* cs = (float*)&pool[0][0][0][0];     // 4 waves * 64 lanes * 32 f = 32KB
    float* ml = cs + 4 * 64 * 32;              // + 512 floats
    const int cidx = (wq * 64 + lane) * 32;
    if (kvh == 1) {
#pragma unroll
        for (int rq = 0; rq < 4; ++rq) {
            f32x4 a, c;
#pragma unroll
            for (int e = 0; e < 4; ++e) { a[e] = o0[4 * rq + e]; c[e] = o1[4 * rq + e]; }
            *(f32x4*)&cs[cidx + 4 * rq] = a;
            *(f32x4*)&cs[cidx + 16 + 4 * rq] = c;
        }
        ml[(wq * 64 + lane) * 2]     = m_;
        ml[(wq * 64 + lane) * 2 + 1] = l_;
    }
    __syncthreads();
    if (kvh == 0) {
        const float m2 = ml[(wq * 64 + lane) * 2];
        const float l2 = ml[(wq * 64 + lane) * 2 + 1];
        const float mM = fmaxf(m_, m2);
        const float sc1 = exp2f(m_ - mM), sc2 = exp2f(m2 - mM);
        const float linv = 1.f / (l_ * sc1 + l2 * sc2);
        ushort* Ao = &AO[((size_t)b * SEQ + q0 + wq * 32 + r31) * D_MODEL + h * 64];
#pragma unroll
        for (int rq = 0; rq < 4; ++rq) {
            f32x4 a = *(const f32x4*)&cs[cidx + 4 * rq];
            f32x4 c = *(const f32x4*)&cs[cidx + 16 + 4 * rq];
            uint2 v0, v1;
            v0.x = cvtpk((o0[4 * rq + 0] * sc1 + a[0] * sc2) * linv,
                         (o0[4 * rq + 1] * sc1 + a[1] * sc2) * linv);
            v0.y = cvtpk((o0[4 * rq + 2] * sc1 + a[2] * sc2) * linv,
                         (o0[4 * rq + 3] * sc1 + a[3] * sc2) * linv);
            v1.x = cvtpk((o1[4 * rq + 0] * sc1 + c[0] * sc2) * linv,
                         (o1[4 * rq + 1] * sc1 + c[1] * sc2) * linv);
            v1.y = cvtpk((o1[4 * rq + 2] * sc1 + c[2] * sc2) * linv,
                         (o1[4 * rq + 3] * sc1 + c[3] * sc2) * linv);
            *(uint2*)&Ao[8 * rq + 4 * hi]      = v0;
            *(uint2*)&Ao[32 + 8 * rq + 4 * hi] = v1;
        }
    }
}

// ---------------------------------------------------------------------------
extern "C" void kernel_launch(void* const* d_in, const int* in_sizes, int n_in,
                              void* d_out, int out_size, void* d_ws, size_t ws_size,
                              hipStream_t stream)
{
    const float* x  = (const float*)d_in[0];
    const float* Wq = (const float*)d_in[1];
    const float* Wk = (const float*)d_in[2];
    const float* Wv = (const float*)d_in[3];
    const float* Wo = (const float*)d_in[4];
    float* out = (float*)d_out;

    ushort* xb   = (ushort*)d_ws;                       // [4096][1024]
    ushort* Wqkv = xb + (size_t)M_TOTAL * D_MODEL;      // [3072][1024]
    ushort* Wob  = Wqkv + (size_t)3 * D_MODEL * D_MODEL;// [1024][1024]
    ushort* q    = Wob + (size_t)D_MODEL * D_MODEL;     // [B,H,S,Dk]
    ushort* k    = q + (size_t)M_TOTAL * D_MODEL;       // [B,H,S,Dk]
    ushort* vt   = k + (size_t)M_TOTAL * D_MODEL;       // [B,H,Dk,S]
    ushort* ao   = vt + (size_t)M_TOTAL * D_MODEL;      // [B,S,D]

    hipLaunchKernelGGL(cast_all, dim3(8192), dim3(256), 0, stream,
                       x, Wq, Wk, Wv, Wo, xb, Wqkv, Wob);

    hipLaunchKernelGGL((gemm_bf16<1>), dim3(3 * D_MODEL / 128, M_TOTAL / 128), dim3(256),
                       0, stream, xb, Wqkv, q, k, vt, M_TOTAL, 3 * D_MODEL, D_MODEL);

    hipLaunchKernelGGL(attn_mfma, dim3(SEQ / 128, N_HEADS, BATCH), dim3(512),
                       0, stream, q, k, vt, ao);

    hipLaunchKernelGGL((gemm_bf16<0>), dim3(D_MODEL / 128, M_TOTAL / 128), dim3(256),
                       0, stream, ao, Wob, out, (void*)0, (void*)0,
                       M_TOTAL, D_MODEL, D_MODEL);
}